// Round 1
// baseline (7192.911 us; speedup 1.0000x reference)
//
#include <hip/hip_runtime.h>

#define BN_EPS 1e-5f
constexpr int BATCH = 32;

static inline int cdiv(int a, int b) { return (a + b - 1) / b; }

// ---------------------------------------------------------------------------
// Generic direct conv, NCHW, OIHW weights. One thread per output element.
// ---------------------------------------------------------------------------
template<int K, int S, int P, bool RELU>
__global__ void conv2d_kernel(const float* __restrict__ in, const float* __restrict__ w,
                              const float* __restrict__ bias, float* __restrict__ out,
                              int N, int Cin, int Hin, int Win, int Cout, int Hout, int Wout)
{
    int idx = blockIdx.x * blockDim.x + threadIdx.x;
    int total = N * Cout * Hout * Wout;
    if (idx >= total) return;
    int ow = idx % Wout;
    int t  = idx / Wout;
    int oh = t % Hout; t /= Hout;
    int oc = t % Cout;
    int n  = t / Cout;
    float acc = bias[oc];
    const float* wp = w  + (size_t)oc * Cin * K * K;
    const float* ip = in + (size_t)n * Cin * Hin * Win;
    for (int ic = 0; ic < Cin; ++ic) {
        const float* iph = ip + (size_t)ic * Hin * Win;
        const float* wph = wp + ic * K * K;
        #pragma unroll
        for (int kh = 0; kh < K; ++kh) {
            int ih = oh * S - P + kh;
            if ((unsigned)ih >= (unsigned)Hin) continue;
            #pragma unroll
            for (int kw = 0; kw < K; ++kw) {
                int iw = ow * S - P + kw;
                if ((unsigned)iw >= (unsigned)Win) continue;
                acc = fmaf(iph[ih * Win + iw], wph[kh * K + kw], acc);
            }
        }
    }
    if (RELU) acc = acc > 0.f ? acc : 0.1f * acc;
    out[idx] = acc;
}

// ---------------------------------------------------------------------------
// BatchNorm stats: one block per (frame, channel). x layout (2, B, C, HW).
// stats[2*(f*C+c)] = mean, stats[2*(f*C+c)+1] = rsqrt(var+eps)   (biased var)
// ---------------------------------------------------------------------------
__global__ void bn_stats_kernel(const float* __restrict__ x, float* __restrict__ stats,
                                int C, int HW)
{
    int c = blockIdx.x % C;
    int f = blockIdx.x / C;
    const float* base = x + (size_t)f * BATCH * C * HW + (size_t)c * HW;
    int total = BATCH * HW;
    float s = 0.f, s2 = 0.f;
    for (int i = threadIdx.x; i < total; i += blockDim.x) {
        int b = i / HW;
        int p = i - b * HW;
        float v = base[(size_t)b * C * HW + p];
        s += v; s2 += v * v;
    }
    __shared__ float sh1[256], sh2[256];
    sh1[threadIdx.x] = s; sh2[threadIdx.x] = s2;
    __syncthreads();
    for (int off = 128; off > 0; off >>= 1) {
        if (threadIdx.x < off) {
            sh1[threadIdx.x] += sh1[threadIdx.x + off];
            sh2[threadIdx.x] += sh2[threadIdx.x + off];
        }
        __syncthreads();
    }
    if (threadIdx.x == 0) {
        float inv = 1.f / (float)total;
        float m   = sh1[0] * inv;
        float var = sh2[0] * inv - m * m;
        stats[2 * blockIdx.x]     = m;
        stats[2 * blockIdx.x + 1] = rsqrtf(var + BN_EPS);
    }
}

// In-place BN + leaky relu over (2, B, C, HW)
__global__ void bn_apply_kernel(float* __restrict__ x, const float* __restrict__ stats,
                                const float* __restrict__ g, const float* __restrict__ be,
                                int C, int HW, int total)
{
    int idx = blockIdx.x * blockDim.x + threadIdx.x;
    if (idx >= total) return;
    int c = (idx / HW) % C;
    int f = idx / (BATCH * C * HW);
    float m = stats[2 * (f * C + c)];
    float r = stats[2 * (f * C + c) + 1];
    float v = (x[idx] - m) * r * g[c] + be[c];
    x[idx] = v > 0.f ? v : 0.1f * v;
}

// ---------------------------------------------------------------------------
// In-place per-position channel L2 normalization. x layout (2*B, C, HW).
// ---------------------------------------------------------------------------
__global__ void l2norm_kernel(float* __restrict__ x, int C, int HW)
{
    int idx = blockIdx.x * blockDim.x + threadIdx.x;
    int totalNP = 2 * BATCH * HW;
    if (idx >= totalNP) return;
    int p = idx % HW;
    int n = idx / HW;
    float* base = x + (size_t)n * C * HW + p;
    float s = 0.f;
    for (int c = 0; c < C; ++c) { float v = base[c * HW]; s += v * v; }
    float inv = 1.f / fmaxf(sqrtf(s), 1e-12f);
    for (int c = 0; c < C; ++c) base[c * HW] *= inv;
}

// ---------------------------------------------------------------------------
// Correlation: x (2, B, 32, 32, 32) L2-normalized. cost (B, 169, 32, 32).
// cost[b, i*13+j, h, w] = sum_c A[b,c,h,w] * B[b,c,h+i-6,w+j-6]  (0 if OOB)
// ---------------------------------------------------------------------------
__global__ void corr_kernel(const float* __restrict__ x, float* __restrict__ cost)
{
    const int HW = 1024;
    int idx = blockIdx.x * blockDim.x + threadIdx.x;
    int total = BATCH * 169 * HW;
    if (idx >= total) return;
    int w_ = idx & 31;
    int h_ = (idx >> 5) & 31;
    int d  = (idx / HW) % 169;
    int b  = idx / (169 * HW);
    int dy = d / 13 - 6;
    int dx = d % 13 - 6;
    int hb = h_ + dy, wb = w_ + dx;
    float s = 0.f;
    if ((unsigned)hb < 32u && (unsigned)wb < 32u) {
        const float* A  = x + ((size_t)b * 32) * HW + h_ * 32 + w_;
        const float* Bv = x + ((size_t)(BATCH + b) * 32) * HW + hb * 32 + wb;
        #pragma unroll 8
        for (int c = 0; c < 32; ++c) s = fmaf(A[c * HW], Bv[c * HW], s);
    }
    cost[idx] = s;
}

// ---------------------------------------------------------------------------
// f1 conv: input = concat(upsample2x(d2)[64ch], fineA[16ch], fineB[16ch]) @64x64
// d2: (B,64,32,32), fine: (2,B,16,64,64), out: (B,64,64,64). lrelu fused.
// ---------------------------------------------------------------------------
__global__ void conv_f1_kernel(const float* __restrict__ d2, const float* __restrict__ fine,
                               const float* __restrict__ w, const float* __restrict__ bias,
                               float* __restrict__ out)
{
    const int HW = 4096;
    int idx = blockIdx.x * blockDim.x + threadIdx.x;
    int total = BATCH * 64 * HW;
    if (idx >= total) return;
    int ow = idx & 63;
    int oh = (idx >> 6) & 63;
    int oc = (idx / HW) & 63;
    int b  = idx / (64 * HW);
    float acc = bias[oc];
    const float* wp = w + (size_t)oc * 96 * 9;
    for (int ci = 0; ci < 96; ++ci) {
        const float* wph = wp + ci * 9;
        #pragma unroll
        for (int kh = 0; kh < 3; ++kh) {
            int ih = oh - 1 + kh;
            if ((unsigned)ih >= 64u) continue;
            #pragma unroll
            for (int kw = 0; kw < 3; ++kw) {
                int iw = ow - 1 + kw;
                if ((unsigned)iw >= 64u) continue;
                float v;
                if (ci < 64)
                    v = d2[((size_t)(b * 64 + ci) * 32 + (ih >> 1)) * 32 + (iw >> 1)];
                else if (ci < 80)
                    v = fine[((size_t)b * 16 + (ci - 64)) * 4096 + ih * 64 + iw];
                else
                    v = fine[((size_t)(BATCH + b) * 16 + (ci - 80)) * 4096 + ih * 64 + iw];
                acc = fmaf(v, wph[kh * 3 + kw], acc);
            }
        }
    }
    acc = acc > 0.f ? acc : 0.1f * acc;
    out[idx] = acc;
}

// ---------------------------------------------------------------------------
// Final 1x1 conv: x (B,32,4096), w (2,32), out (B,2,4096). No activation.
// ---------------------------------------------------------------------------
__global__ void conv_out_kernel(const float* __restrict__ x, const float* __restrict__ w,
                                const float* __restrict__ bias, float* __restrict__ out)
{
    int idx = blockIdx.x * blockDim.x + threadIdx.x;
    int total = BATCH * 2 * 4096;
    if (idx >= total) return;
    int p  = idx & 4095;
    int oc = (idx >> 12) & 1;
    int b  = idx >> 13;
    float acc = bias[oc];
    const float* xp = x + (size_t)b * 32 * 4096 + p;
    const float* wp = w + oc * 32;
    #pragma unroll
    for (int c = 0; c < 32; ++c) acc = fmaf(xp[c * 4096], wp[c], acc);
    out[idx] = acc;
}

// ---------------------------------------------------------------------------
extern "C" void kernel_launch(void* const* d_in, const int* in_sizes, int n_in,
                              void* d_out, int out_size, void* d_ws, size_t ws_size,
                              hipStream_t stream)
{
    const float* frameA = (const float*)d_in[0];
    const float* frameB = (const float*)d_in[1];
    const float* w1  = (const float*)d_in[2];
    const float* b1  = (const float*)d_in[3];
    const float* g1  = (const float*)d_in[4];
    const float* be1 = (const float*)d_in[5];
    const float* w2  = (const float*)d_in[6];
    const float* b2  = (const float*)d_in[7];
    const float* g2  = (const float*)d_in[8];
    const float* be2 = (const float*)d_in[9];
    const float* w3  = (const float*)d_in[10];
    const float* b3  = (const float*)d_in[11];
    const float* g3  = (const float*)d_in[12];
    const float* be3 = (const float*)d_in[13];
    const float* wc1 = (const float*)d_in[14];
    const float* bc1 = (const float*)d_in[15];
    const float* wc2 = (const float*)d_in[16];
    const float* bc2 = (const float*)d_in[17];
    const float* wf1 = (const float*)d_in[18];
    const float* bf1 = (const float*)d_in[19];
    const float* wf2 = (const float*)d_in[20];
    const float* bf2 = (const float*)d_in[21];
    const float* wo  = (const float*)d_in[22];
    const float* bo  = (const float*)d_in[23];

    // workspace layout (floats)
    float* ws     = (float*)d_ws;
    float* fine   = ws;                  // (2,32,16,64,64)  4,194,304
    float* hbuf   = fine + 4194304;      // (2,32,32,32,32)  2,097,152  [reused: d2 (32,64,32,32)]
    float* coarse = hbuf + 2097152;      // (2,32,32,32,32)  2,097,152
    float* cost   = coarse + 2097152;    // (32,169,32,32)   5,537,792  [reused: f2 out (32,32,64,64)]
    float* d1     = cost + 5537792;      // (32,128,32,32)   4,194,304
    float* f1o    = d1 + 4194304;        // (32,64,64,64)    8,388,608
    float* stats  = f1o + 8388608;       // 128

    const int T = 256;

    // --- encoder conv1 (7x7, pad3) both frames
    {
        int total = BATCH * 16 * 4096;
        conv2d_kernel<7,1,3,false><<<cdiv(total,T), T, 0, stream>>>(frameA, w1, b1, fine,
                                                                    BATCH, 1, 64, 64, 16, 64, 64);
        conv2d_kernel<7,1,3,false><<<cdiv(total,T), T, 0, stream>>>(frameB, w1, b1, fine + total,
                                                                    BATCH, 1, 64, 64, 16, 64, 64);
        bn_stats_kernel<<<2 * 16, T, 0, stream>>>(fine, stats, 16, 4096);
        bn_apply_kernel<<<cdiv(2 * total, T), T, 0, stream>>>(fine, stats, g1, be1, 16, 4096, 2 * total);
    }
    // --- encoder conv2 (5x5, stride2, pad2): treat (2,B) as batch 64
    {
        int total = 2 * BATCH * 32 * 1024;
        conv2d_kernel<5,2,2,false><<<cdiv(total,T), T, 0, stream>>>(fine, w2, b2, hbuf,
                                                                    2 * BATCH, 16, 64, 64, 32, 32, 32);
        bn_stats_kernel<<<2 * 32, T, 0, stream>>>(hbuf, stats, 32, 1024);
        bn_apply_kernel<<<cdiv(total,T), T, 0, stream>>>(hbuf, stats, g2, be2, 32, 1024, total);
    }
    // --- encoder conv3 (3x3, pad1)
    {
        int total = 2 * BATCH * 32 * 1024;
        conv2d_kernel<3,1,1,false><<<cdiv(total,T), T, 0, stream>>>(hbuf, w3, b3, coarse,
                                                                    2 * BATCH, 32, 32, 32, 32, 32, 32);
        bn_stats_kernel<<<2 * 32, T, 0, stream>>>(coarse, stats, 32, 1024);
        bn_apply_kernel<<<cdiv(total,T), T, 0, stream>>>(coarse, stats, g3, be3, 32, 1024, total);
    }
    // --- L2 norm + correlation
    l2norm_kernel<<<cdiv(2 * BATCH * 1024, T), T, 0, stream>>>(coarse, 32, 1024);
    corr_kernel<<<cdiv(BATCH * 169 * 1024, T), T, 0, stream>>>(coarse, cost);

    // --- decoder
    {
        int total = BATCH * 128 * 1024;
        conv2d_kernel<3,1,1,true><<<cdiv(total,T), T, 0, stream>>>(cost, wc1, bc1, d1,
                                                                   BATCH, 169, 32, 32, 128, 32, 32);
    }
    {
        int total = BATCH * 64 * 1024;
        conv2d_kernel<3,1,1,true><<<cdiv(total,T), T, 0, stream>>>(d1, wc2, bc2, hbuf /*d2*/,
                                                                   BATCH, 128, 32, 32, 64, 32, 32);
    }
    conv_f1_kernel<<<cdiv(BATCH * 64 * 4096, T), T, 0, stream>>>(hbuf, fine, wf1, bf1, f1o);
    {
        int total = BATCH * 32 * 4096;
        conv2d_kernel<3,1,1,true><<<cdiv(total,T), T, 0, stream>>>(f1o, wf2, bf2, cost /*f2o*/,
                                                                   BATCH, 64, 64, 64, 32, 64, 64);
    }
    conv_out_kernel<<<cdiv(BATCH * 2 * 4096, T), T, 0, stream>>>(cost, wo, bo, (float*)d_out);
}

// Round 2
// 1979.792 us; speedup vs baseline: 3.6332x; 3.6332x over previous
//
#include <hip/hip_runtime.h>

#define BN_EPS 1e-5f
constexpr int BATCH = 32;

static inline int cdiv(int a, int b) { return (a + b - 1) / b; }

__device__ __forceinline__ float lrelu(float v) { return v > 0.f ? v : 0.1f * v; }

// ---------------------------------------------------------------------------
// Tiled 3x3 pad-1 conv, NCHW. Block: one (n, ocg, 32x32 spatial tile).
// 256 threads = 16x16 grid; each thread: strided 2x2 micro-tile x OCB outch.
// Input staged in LDS in 4-channel chunks (34x34 halo, row stride 40).
// ---------------------------------------------------------------------------
template<int OCB, bool RELU>
__global__ __launch_bounds__(256) void conv3x3_tiled(
    const float* __restrict__ in, const float* __restrict__ w,
    const float* __restrict__ bias, float* __restrict__ out,
    int CIN, int H, int COUT)
{
    __shared__ float s_in[4][34][40];
    __shared__ float s_w[4][9][OCB];

    const int tid = threadIdx.x;
    const int tx = tid & 15, ty = tid >> 4;
    const int tilesx = H >> 5;
    const int tile = blockIdx.x;
    const int x0 = (tile % tilesx) << 5;
    const int y0 = (tile / tilesx) << 5;
    const int ocg = blockIdx.y;
    const int n = blockIdx.z;
    const int ocbase = ocg * OCB;

    float acc[OCB][4];
    #pragma unroll
    for (int oc = 0; oc < OCB; ++oc) {
        float bv = bias[ocbase + oc];
        acc[oc][0] = bv; acc[oc][1] = bv; acc[oc][2] = bv; acc[oc][3] = bv;
    }

    for (int c0 = 0; c0 < CIN; c0 += 4) {
        // stage weights: layout s_w[ic][k][oc]
        for (int t = tid; t < 4 * 9 * OCB; t += 256) {
            int oc = t % OCB;
            int k  = (t / OCB) % 9;
            int ic = t / (OCB * 9);
            int gc = c0 + ic;
            float v = 0.f;
            if (gc < CIN) v = w[((size_t)(ocbase + oc) * CIN + gc) * 9 + k];
            s_w[ic][k][oc] = v;
        }
        // stage input: 4 channels x 34x34 halo
        for (int t = tid; t < 4 * 34 * 34; t += 256) {
            int ic = t / 1156;
            int r  = t - ic * 1156;
            int y = r / 34, x = r - (r / 34) * 34;
            int gy = y0 + y - 1, gx = x0 + x - 1;
            int gc = c0 + ic;
            float v = 0.f;
            if (gc < CIN && (unsigned)gy < (unsigned)H && (unsigned)gx < (unsigned)H)
                v = in[((size_t)n * CIN + gc) * H * H + gy * H + gx];
            s_in[ic][y][x] = v;
        }
        __syncthreads();

        #pragma unroll
        for (int ic = 0; ic < 4; ++ic) {
            #pragma unroll
            for (int kh = 0; kh < 3; ++kh) {
                #pragma unroll
                for (int kw = 0; kw < 3; ++kw) {
                    float i00 = s_in[ic][ty + kh][tx + kw];
                    float i01 = s_in[ic][ty + kh][tx + 16 + kw];
                    float i10 = s_in[ic][ty + 16 + kh][tx + kw];
                    float i11 = s_in[ic][ty + 16 + kh][tx + 16 + kw];
                    #pragma unroll
                    for (int oc = 0; oc < OCB; ++oc) {
                        float wv = s_w[ic][kh * 3 + kw][oc];
                        acc[oc][0] = fmaf(i00, wv, acc[oc][0]);
                        acc[oc][1] = fmaf(i01, wv, acc[oc][1]);
                        acc[oc][2] = fmaf(i10, wv, acc[oc][2]);
                        acc[oc][3] = fmaf(i11, wv, acc[oc][3]);
                    }
                }
            }
        }
        __syncthreads();
    }

    #pragma unroll
    for (int oc = 0; oc < OCB; ++oc) {
        #pragma unroll
        for (int i = 0; i < 2; ++i) {
            #pragma unroll
            for (int j = 0; j < 2; ++j) {
                int oy = y0 + ty + i * 16, ox = x0 + tx + j * 16;
                float v = acc[oc][i * 2 + j];
                if (RELU) v = lrelu(v);
                out[((size_t)n * COUT + ocbase + oc) * H * H + oy * H + ox] = v;
            }
        }
    }
}

// ---------------------------------------------------------------------------
// f1 conv: gathered input = concat(upsample2x(d2)[64], fineA[16], fineB[16])
// Same compute structure as conv3x3_tiled<8,true>, CIN=96, H=64.
// ---------------------------------------------------------------------------
__global__ __launch_bounds__(256) void conv_f1_tiled(
    const float* __restrict__ d2, const float* __restrict__ fine,
    const float* __restrict__ w, const float* __restrict__ bias,
    float* __restrict__ out)
{
    constexpr int OCB = 8, CIN = 96, H = 64, COUT = 64;
    __shared__ float s_in[4][34][40];
    __shared__ float s_w[4][9][OCB];

    const int tid = threadIdx.x;
    const int tx = tid & 15, ty = tid >> 4;
    const int tile = blockIdx.x;
    const int x0 = (tile & 1) << 5;
    const int y0 = (tile >> 1) << 5;
    const int ocg = blockIdx.y;
    const int n = blockIdx.z;
    const int ocbase = ocg * OCB;

    float acc[OCB][4];
    #pragma unroll
    for (int oc = 0; oc < OCB; ++oc) {
        float bv = bias[ocbase + oc];
        acc[oc][0] = bv; acc[oc][1] = bv; acc[oc][2] = bv; acc[oc][3] = bv;
    }

    for (int c0 = 0; c0 < CIN; c0 += 4) {
        for (int t = tid; t < 4 * 9 * OCB; t += 256) {
            int oc = t % OCB;
            int k  = (t / OCB) % 9;
            int ic = t / (OCB * 9);
            s_w[ic][k][oc] = w[((size_t)(ocbase + oc) * CIN + c0 + ic) * 9 + k];
        }
        for (int t = tid; t < 4 * 34 * 34; t += 256) {
            int ic = t / 1156;
            int r  = t - ic * 1156;
            int y = r / 34, x = r - (r / 34) * 34;
            int gy = y0 + y - 1, gx = x0 + x - 1;
            int gc = c0 + ic;
            float v = 0.f;
            if ((unsigned)gy < 64u && (unsigned)gx < 64u) {
                if (gc < 64)
                    v = d2[((size_t)(n * 64 + gc) * 32 + (gy >> 1)) * 32 + (gx >> 1)];
                else if (gc < 80)
                    v = fine[((size_t)n * 16 + (gc - 64)) * 4096 + gy * 64 + gx];
                else
                    v = fine[((size_t)(BATCH + n) * 16 + (gc - 80)) * 4096 + gy * 64 + gx];
            }
            s_in[ic][y][x] = v;
        }
        __syncthreads();

        #pragma unroll
        for (int ic = 0; ic < 4; ++ic) {
            #pragma unroll
            for (int kh = 0; kh < 3; ++kh) {
                #pragma unroll
                for (int kw = 0; kw < 3; ++kw) {
                    float i00 = s_in[ic][ty + kh][tx + kw];
                    float i01 = s_in[ic][ty + kh][tx + 16 + kw];
                    float i10 = s_in[ic][ty + 16 + kh][tx + kw];
                    float i11 = s_in[ic][ty + 16 + kh][tx + 16 + kw];
                    #pragma unroll
                    for (int oc = 0; oc < OCB; ++oc) {
                        float wv = s_w[ic][kh * 3 + kw][oc];
                        acc[oc][0] = fmaf(i00, wv, acc[oc][0]);
                        acc[oc][1] = fmaf(i01, wv, acc[oc][1]);
                        acc[oc][2] = fmaf(i10, wv, acc[oc][2]);
                        acc[oc][3] = fmaf(i11, wv, acc[oc][3]);
                    }
                }
            }
        }
        __syncthreads();
    }

    #pragma unroll
    for (int oc = 0; oc < OCB; ++oc) {
        #pragma unroll
        for (int i = 0; i < 2; ++i) {
            #pragma unroll
            for (int j = 0; j < 2; ++j) {
                int oy = y0 + ty + i * 16, ox = x0 + tx + j * 16;
                out[((size_t)n * COUT + ocbase + oc) * 4096 + oy * 64 + ox] =
                    lrelu(acc[oc][i * 2 + j]);
            }
        }
    }
}

// ---------------------------------------------------------------------------
// Encoder conv1: 7x7 pad3, Cin=1, Cout=16, 64x64. Block: (n, ocg of 8, tile).
// ---------------------------------------------------------------------------
__global__ __launch_bounds__(256) void conv1_tiled(
    const float* __restrict__ in, const float* __restrict__ w,
    const float* __restrict__ bias, float* __restrict__ out)
{
    __shared__ float s_in[38][40];
    __shared__ float s_w[49][8];

    const int tid = threadIdx.x;
    const int tx = tid & 15, ty = tid >> 4;
    const int tile = blockIdx.x;
    const int x0 = (tile & 1) << 5;
    const int y0 = (tile >> 1) << 5;
    const int ocbase = blockIdx.y * 8;
    const int n = blockIdx.z;

    for (int t = tid; t < 49 * 8; t += 256) {
        int oc = t & 7, k = t >> 3;
        s_w[k][oc] = w[(ocbase + oc) * 49 + k];
    }
    for (int t = tid; t < 38 * 38; t += 256) {
        int y = t / 38, x = t - (t / 38) * 38;
        int gy = y0 + y - 3, gx = x0 + x - 3;
        float v = 0.f;
        if ((unsigned)gy < 64u && (unsigned)gx < 64u)
            v = in[(size_t)n * 4096 + gy * 64 + gx];
        s_in[y][x] = v;
    }
    __syncthreads();

    float acc[8][4];
    #pragma unroll
    for (int oc = 0; oc < 8; ++oc) {
        float bv = bias[ocbase + oc];
        acc[oc][0] = bv; acc[oc][1] = bv; acc[oc][2] = bv; acc[oc][3] = bv;
    }

    #pragma unroll
    for (int kh = 0; kh < 7; ++kh) {
        #pragma unroll
        for (int kw = 0; kw < 7; ++kw) {
            float i00 = s_in[ty + kh][tx + kw];
            float i01 = s_in[ty + kh][tx + 16 + kw];
            float i10 = s_in[ty + 16 + kh][tx + kw];
            float i11 = s_in[ty + 16 + kh][tx + 16 + kw];
            #pragma unroll
            for (int oc = 0; oc < 8; ++oc) {
                float wv = s_w[kh * 7 + kw][oc];
                acc[oc][0] = fmaf(i00, wv, acc[oc][0]);
                acc[oc][1] = fmaf(i01, wv, acc[oc][1]);
                acc[oc][2] = fmaf(i10, wv, acc[oc][2]);
                acc[oc][3] = fmaf(i11, wv, acc[oc][3]);
            }
        }
    }

    #pragma unroll
    for (int oc = 0; oc < 8; ++oc) {
        #pragma unroll
        for (int i = 0; i < 2; ++i) {
            #pragma unroll
            for (int j = 0; j < 2; ++j) {
                int oy = y0 + ty + i * 16, ox = x0 + tx + j * 16;
                out[((size_t)n * 16 + ocbase + oc) * 4096 + oy * 64 + ox] =
                    acc[oc][i * 2 + j];
            }
        }
    }
}

// ---------------------------------------------------------------------------
// Encoder conv2: 5x5 stride2 pad2, Cin=16, Cout=32, 64->32. N=64 frames.
// Block: (n, ocg of 4). Full 32x32 out tile. 2-ch input chunks (67x67 halo).
// ---------------------------------------------------------------------------
__global__ __launch_bounds__(256) void conv2_tiled(
    const float* __restrict__ in, const float* __restrict__ w,
    const float* __restrict__ bias, float* __restrict__ out)
{
    __shared__ float s_in[2][67][68];
    __shared__ float s_w[2][25][4];

    const int tid = threadIdx.x;
    const int tx = tid & 15, ty = tid >> 4;
    const int ocbase = blockIdx.y * 4;
    const int n = blockIdx.z;

    float acc[4][4];
    #pragma unroll
    for (int oc = 0; oc < 4; ++oc) {
        float bv = bias[ocbase + oc];
        acc[oc][0] = bv; acc[oc][1] = bv; acc[oc][2] = bv; acc[oc][3] = bv;
    }

    for (int c0 = 0; c0 < 16; c0 += 2) {
        for (int t = tid; t < 2 * 25 * 4; t += 256) {
            int oc = t & 3;
            int k  = (t >> 2) % 25;
            int ic = t / 100;
            s_w[ic][k][oc] = w[((ocbase + oc) * 16 + c0 + ic) * 25 + k];
        }
        for (int t = tid; t < 2 * 67 * 67; t += 256) {
            int ic = t / 4489;
            int r  = t - ic * 4489;
            int y = r / 67, x = r - (r / 67) * 67;
            int gy = y - 2, gx = x - 2;
            float v = 0.f;
            if ((unsigned)gy < 64u && (unsigned)gx < 64u)
                v = in[((size_t)n * 16 + c0 + ic) * 4096 + gy * 64 + gx];
            s_in[ic][y][x] = v;
        }
        __syncthreads();

        #pragma unroll
        for (int ic = 0; ic < 2; ++ic) {
            #pragma unroll
            for (int kh = 0; kh < 5; ++kh) {
                #pragma unroll
                for (int kw = 0; kw < 5; ++kw) {
                    float i00 = s_in[ic][2 * ty + kh][2 * tx + kw];
                    float i01 = s_in[ic][2 * ty + kh][2 * tx + 32 + kw];
                    float i10 = s_in[ic][2 * ty + 32 + kh][2 * tx + kw];
                    float i11 = s_in[ic][2 * ty + 32 + kh][2 * tx + 32 + kw];
                    #pragma unroll
                    for (int oc = 0; oc < 4; ++oc) {
                        float wv = s_w[ic][kh * 5 + kw][oc];
                        acc[oc][0] = fmaf(i00, wv, acc[oc][0]);
                        acc[oc][1] = fmaf(i01, wv, acc[oc][1]);
                        acc[oc][2] = fmaf(i10, wv, acc[oc][2]);
                        acc[oc][3] = fmaf(i11, wv, acc[oc][3]);
                    }
                }
            }
        }
        __syncthreads();
    }

    #pragma unroll
    for (int oc = 0; oc < 4; ++oc) {
        #pragma unroll
        for (int i = 0; i < 2; ++i) {
            #pragma unroll
            for (int j = 0; j < 2; ++j) {
                int oy = ty + i * 16, ox = tx + j * 16;
                out[((size_t)n * 32 + ocbase + oc) * 1024 + oy * 32 + ox] =
                    acc[oc][i * 2 + j];
            }
        }
    }
}

// ---------------------------------------------------------------------------
// BatchNorm stats: one block per (frame, channel). x layout (2, B, C, HW).
// ---------------------------------------------------------------------------
__global__ void bn_stats_kernel(const float* __restrict__ x, float* __restrict__ stats,
                                int C, int HW)
{
    int c = blockIdx.x % C;
    int f = blockIdx.x / C;
    const float* base = x + (size_t)f * BATCH * C * HW + (size_t)c * HW;
    int total = BATCH * HW;
    float s = 0.f, s2 = 0.f;
    for (int i = threadIdx.x; i < total; i += blockDim.x) {
        int b = i / HW;
        int p = i - b * HW;
        float v = base[(size_t)b * C * HW + p];
        s += v; s2 += v * v;
    }
    __shared__ float sh1[256], sh2[256];
    sh1[threadIdx.x] = s; sh2[threadIdx.x] = s2;
    __syncthreads();
    for (int off = 128; off > 0; off >>= 1) {
        if (threadIdx.x < off) {
            sh1[threadIdx.x] += sh1[threadIdx.x + off];
            sh2[threadIdx.x] += sh2[threadIdx.x + off];
        }
        __syncthreads();
    }
    if (threadIdx.x == 0) {
        float inv = 1.f / (float)total;
        float m   = sh1[0] * inv;
        float var = sh2[0] * inv - m * m;
        stats[2 * blockIdx.x]     = m;
        stats[2 * blockIdx.x + 1] = rsqrtf(var + BN_EPS);
    }
}

__global__ void bn_apply_kernel(float* __restrict__ x, const float* __restrict__ stats,
                                const float* __restrict__ g, const float* __restrict__ be,
                                int C, int HW, int total)
{
    int idx = blockIdx.x * blockDim.x + threadIdx.x;
    if (idx >= total) return;
    int c = (idx / HW) % C;
    int f = idx / (BATCH * C * HW);
    float m = stats[2 * (f * C + c)];
    float r = stats[2 * (f * C + c) + 1];
    float v = (x[idx] - m) * r * g[c] + be[c];
    x[idx] = lrelu(v);
}

// ---------------------------------------------------------------------------
__global__ void l2norm_kernel(float* __restrict__ x, int C, int HW)
{
    int idx = blockIdx.x * blockDim.x + threadIdx.x;
    int totalNP = 2 * BATCH * HW;
    if (idx >= totalNP) return;
    int p = idx % HW;
    int n = idx / HW;
    float* base = x + (size_t)n * C * HW + p;
    float s = 0.f;
    for (int c = 0; c < C; ++c) { float v = base[c * HW]; s += v * v; }
    float inv = 1.f / fmaxf(sqrtf(s), 1e-12f);
    for (int c = 0; c < C; ++c) base[c * HW] *= inv;
}

// ---------------------------------------------------------------------------
__global__ void corr_kernel(const float* __restrict__ x, float* __restrict__ cost)
{
    const int HW = 1024;
    int idx = blockIdx.x * blockDim.x + threadIdx.x;
    int total = BATCH * 169 * HW;
    if (idx >= total) return;
    int w_ = idx & 31;
    int h_ = (idx >> 5) & 31;
    int d  = (idx / HW) % 169;
    int b  = idx / (169 * HW);
    int dy = d / 13 - 6;
    int dx = d % 13 - 6;
    int hb = h_ + dy, wb = w_ + dx;
    float s = 0.f;
    if ((unsigned)hb < 32u && (unsigned)wb < 32u) {
        const float* A  = x + ((size_t)b * 32) * HW + h_ * 32 + w_;
        const float* Bv = x + ((size_t)(BATCH + b) * 32) * HW + hb * 32 + wb;
        #pragma unroll 8
        for (int c = 0; c < 32; ++c) s = fmaf(A[c * HW], Bv[c * HW], s);
    }
    cost[idx] = s;
}

// ---------------------------------------------------------------------------
__global__ void conv_out_kernel(const float* __restrict__ x, const float* __restrict__ w,
                                const float* __restrict__ bias, float* __restrict__ out)
{
    int idx = blockIdx.x * blockDim.x + threadIdx.x;
    int total = BATCH * 2 * 4096;
    if (idx >= total) return;
    int p  = idx & 4095;
    int oc = (idx >> 12) & 1;
    int b  = idx >> 13;
    float acc = bias[oc];
    const float* xp = x + (size_t)b * 32 * 4096 + p;
    const float* wp = w + oc * 32;
    #pragma unroll
    for (int c = 0; c < 32; ++c) acc = fmaf(xp[c * 4096], wp[c], acc);
    out[idx] = acc;
}

// ---------------------------------------------------------------------------
extern "C" void kernel_launch(void* const* d_in, const int* in_sizes, int n_in,
                              void* d_out, int out_size, void* d_ws, size_t ws_size,
                              hipStream_t stream)
{
    const float* frameA = (const float*)d_in[0];
    const float* frameB = (const float*)d_in[1];
    const float* w1  = (const float*)d_in[2];
    const float* b1  = (const float*)d_in[3];
    const float* g1  = (const float*)d_in[4];
    const float* be1 = (const float*)d_in[5];
    const float* w2  = (const float*)d_in[6];
    const float* b2  = (const float*)d_in[7];
    const float* g2  = (const float*)d_in[8];
    const float* be2 = (const float*)d_in[9];
    const float* w3  = (const float*)d_in[10];
    const float* b3  = (const float*)d_in[11];
    const float* g3  = (const float*)d_in[12];
    const float* be3 = (const float*)d_in[13];
    const float* wc1 = (const float*)d_in[14];
    const float* bc1 = (const float*)d_in[15];
    const float* wc2 = (const float*)d_in[16];
    const float* bc2 = (const float*)d_in[17];
    const float* wf1 = (const float*)d_in[18];
    const float* bf1 = (const float*)d_in[19];
    const float* wf2 = (const float*)d_in[20];
    const float* bf2 = (const float*)d_in[21];
    const float* wo  = (const float*)d_in[22];
    const float* bo  = (const float*)d_in[23];

    // workspace layout (floats)
    float* ws     = (float*)d_ws;
    float* fine   = ws;                  // (2,32,16,64,64)  4,194,304
    float* hbuf   = fine + 4194304;      // (2,32,32,32,32)  2,097,152  [reused: d2]
    float* coarse = hbuf + 2097152;      // (2,32,32,32,32)  2,097,152
    float* cost   = coarse + 2097152;    // (32,169,32,32)   5,537,792  [reused: f2o]
    float* d1     = cost + 5537792;      // (32,128,32,32)   4,194,304
    float* f1o    = d1 + 4194304;        // (32,64,64,64)    8,388,608
    float* stats  = f1o + 8388608;       // 128

    const int T = 256;

    // --- encoder conv1 (7x7 pad3) both frames + BN + lrelu
    {
        conv1_tiled<<<dim3(4, 2, BATCH), 256, 0, stream>>>(frameA, w1, b1, fine);
        conv1_tiled<<<dim3(4, 2, BATCH), 256, 0, stream>>>(frameB, w1, b1, fine + BATCH * 16 * 4096);
        int total2 = 2 * BATCH * 16 * 4096;
        bn_stats_kernel<<<2 * 16, T, 0, stream>>>(fine, stats, 16, 4096);
        bn_apply_kernel<<<cdiv(total2, T), T, 0, stream>>>(fine, stats, g1, be1, 16, 4096, total2);
    }
    // --- encoder conv2 (5x5 s2 pad2): N=64 frames
    {
        conv2_tiled<<<dim3(1, 8, 2 * BATCH), 256, 0, stream>>>(fine, w2, b2, hbuf);
        int total = 2 * BATCH * 32 * 1024;
        bn_stats_kernel<<<2 * 32, T, 0, stream>>>(hbuf, stats, 32, 1024);
        bn_apply_kernel<<<cdiv(total, T), T, 0, stream>>>(hbuf, stats, g2, be2, 32, 1024, total);
    }
    // --- encoder conv3 (3x3 pad1): N=64
    {
        conv3x3_tiled<4, false><<<dim3(1, 8, 2 * BATCH), 256, 0, stream>>>(hbuf, w3, b3, coarse, 32, 32, 32);
        int total = 2 * BATCH * 32 * 1024;
        bn_stats_kernel<<<2 * 32, T, 0, stream>>>(coarse, stats, 32, 1024);
        bn_apply_kernel<<<cdiv(total, T), T, 0, stream>>>(coarse, stats, g3, be3, 32, 1024, total);
    }
    // --- L2 norm + correlation
    l2norm_kernel<<<cdiv(2 * BATCH * 1024, T), T, 0, stream>>>(coarse, 32, 1024);
    corr_kernel<<<cdiv(BATCH * 169 * 1024, T), T, 0, stream>>>(coarse, cost);

    // --- decoder
    conv3x3_tiled<8, true><<<dim3(1, 16, BATCH), 256, 0, stream>>>(cost, wc1, bc1, d1, 169, 32, 128);
    conv3x3_tiled<4, true><<<dim3(1, 16, BATCH), 256, 0, stream>>>(d1, wc2, bc2, hbuf /*d2*/, 128, 32, 64);
    conv_f1_tiled<<<dim3(4, 8, BATCH), 256, 0, stream>>>(hbuf, fine, wf1, bf1, f1o);
    conv3x3_tiled<8, true><<<dim3(4, 4, BATCH), 256, 0, stream>>>(f1o, wf2, bf2, cost /*f2o*/, 64, 64, 32);
    conv_out_kernel<<<cdiv(BATCH * 2 * 4096, T), T, 0, stream>>>(cost, wo, bo, (float*)d_out);
}

// Round 3
// 668.766 us; speedup vs baseline: 10.7555x; 2.9604x over previous
//
#include <hip/hip_runtime.h>

typedef __attribute__((ext_vector_type(4))) float f32x4;
typedef __attribute__((ext_vector_type(8))) short bf16x8;

#define BN_EPS 1e-5f
constexpr int BATCH = 32;

static inline int cdiv(int a, int b) { return (a + b - 1) / b; }

__device__ __forceinline__ float lrelu(float v) { return v > 0.f ? v : 0.1f * v; }

// f32 -> bf16 round-to-nearest-even
__device__ __forceinline__ unsigned short f2bf(float f) {
    unsigned u = __float_as_uint(f);
    u = (u + 0x7FFFu + ((u >> 16) & 1u)) >> 16;
    return (unsigned short)u;
}
__device__ __forceinline__ float bf2f(unsigned short s) {
    return __uint_as_float(((unsigned)s) << 16);
}

// ---------------------------------------------------------------------------
// Weight prep: OIHW f32 -> [tap][COUT][CINP] bf16 with Cin zero-pad.
// ---------------------------------------------------------------------------
__global__ void prep_w_kernel(const float* __restrict__ src, unsigned short* __restrict__ dst,
                              int COUT, int CINS, int CINP)
{
    int idx = blockIdx.x * blockDim.x + threadIdx.x;
    int total = 9 * COUT * CINP;
    if (idx >= total) return;
    int ic  = idx % CINP;
    int oc  = (idx / CINP) % COUT;
    int tap = idx / (CINP * COUT);
    float v = (ic < CINS) ? src[((size_t)oc * CINS + ic) * 9 + tap] : 0.f;
    dst[((size_t)tap * COUT + oc) * CINP + ic] = f2bf(v);
}

// ---------------------------------------------------------------------------
// MFMA implicit-GEMM 3x3 pad-1 conv, NHWC bf16 in/out, fp32 accum, lrelu.
// Tap-decomposed: D += W_tap (COUT x CIN) * X_shift (CIN x positions).
// Block: 256 thr = 4 waves; tile = MB ocs x (TH x 16) positions.
// MODE 0: in = NHWC bf16 [n][H][H][CIN].
// MODE 1 (f1): ch 0-63 = upsample2x(d2 NHWC[n][32][32][64]), 64-79 fineA,
//              80-95 fineB from in2 = [2][B][64][64][16].
// ---------------------------------------------------------------------------
template<int CIN, int COUT, int H, int TH, int MODE>
__global__ __launch_bounds__(256) void conv3x3_mfma(
    const unsigned short* __restrict__ in,
    const unsigned short* __restrict__ in2,
    const unsigned short* __restrict__ wT,   // [9][COUT][CIN] bf16
    const float* __restrict__ bias,
    unsigned short* __restrict__ out)        // NHWC bf16 [n][H][H][COUT]
{
    constexpr int MB = (COUT >= 64) ? 64 : COUT;   // 64 or 32
    constexpr int MFRAGS = MB / 16;                // 4 or 2
    constexpr int NFRAGS = TH;                     // 8 or 16 (tile width 16)
    constexpr int WM = 2;
    constexpr int MW = MFRAGS / WM;                // 2 or 1
    constexpr int NW = 4 / MW;                     // 2 or 4
    constexpr int WN = NFRAGS / NW;                // 4

    __shared__ unsigned short s_w[9 * MB * 32];
    __shared__ unsigned short s_in[(TH + 2) * 18 * 32];

    const int tid  = threadIdx.x;
    const int wid  = tid >> 6;
    const int lane = tid & 63;
    const int l15  = lane & 15;
    const int kg   = lane >> 4;                    // 0..3
    constexpr int TILESX = H / 16;
    const int bx = blockIdx.x;
    const int x0 = (bx % TILESX) * 16;
    const int y0 = (bx / TILESX) * TH;
    const int ocbase = blockIdx.y * MB;
    const int n = blockIdx.z;

    const int mw = wid % MW;
    const int nw = wid / MW;

    f32x4 acc[WM][WN];
    #pragma unroll
    for (int i = 0; i < WM; ++i) {
        #pragma unroll
        for (int r = 0; r < 4; ++r) {
            float bv = bias[ocbase + (mw * WM + i) * 16 + kg * 4 + r];
            #pragma unroll
            for (int j = 0; j < WN; ++j) acc[i][j][r] = bv;
        }
    }

    for (int c0 = 0; c0 < CIN; c0 += 32) {
        // stage weights: 9*MB rows x 32 ch (64B rows, 16B units)
        for (int t = tid; t < 9 * MB * 4; t += 256) {
            int sub = t & 3;
            int row = t >> 2;                      // tap*MB + oc
            int tap = row / MB, oc = row % MB;
            const unsigned short* src = wT + ((size_t)(tap * COUT + ocbase + oc) * CIN + c0) + sub * 8;
            *(int4*)&s_w[row * 32 + sub * 8] = *(const int4*)src;
        }
        // stage input halo: (TH+2) x 18 x 32ch
        for (int t = tid; t < (TH + 2) * 18 * 4; t += 256) {
            int sub = t & 3;
            int p = t >> 2;
            int y = p / 18, x = p - y * 18;
            int gy = y0 - 1 + y, gx = x0 - 1 + x;
            int4 v = {0, 0, 0, 0};
            if ((unsigned)gy < (unsigned)H && (unsigned)gx < (unsigned)H) {
                if (MODE == 0) {
                    v = *(const int4*)&in[((size_t)(n * H + gy) * H + gx) * CIN + c0 + sub * 8];
                } else {
                    if (c0 < 64) {
                        v = *(const int4*)&in[((size_t)(n * 32 + (gy >> 1)) * 32 + (gx >> 1)) * 64 + c0 + sub * 8];
                    } else {
                        int f  = sub >> 1;          // 0: fineA, 1: fineB
                        int cc = (sub & 1) * 8;
                        v = *(const int4*)&in2[((size_t)((f * BATCH + n) * 64 + gy) * 64 + gx) * 16 + cc];
                    }
                }
            }
            *(int4*)&s_in[p * 32 + sub * 8] = v;
        }
        __syncthreads();

        #pragma unroll
        for (int tap = 0; tap < 9; ++tap) {
            const int kh = tap / 3, kw = tap - (tap / 3) * 3;
            bf16x8 a[WM], b[WN];
            #pragma unroll
            for (int i = 0; i < WM; ++i) {
                int mf = mw * WM + i;
                a[i] = *(const bf16x8*)&s_w[(tap * MB + mf * 16 + l15) * 32 + kg * 8];
            }
            #pragma unroll
            for (int j = 0; j < WN; ++j) {
                int nf = nw * WN + j;
                b[j] = *(const bf16x8*)&s_in[((nf + kh) * 18 + l15 + kw) * 32 + kg * 8];
            }
            #pragma unroll
            for (int i = 0; i < WM; ++i)
                #pragma unroll
                for (int j = 0; j < WN; ++j)
                    acc[i][j] = __builtin_amdgcn_mfma_f32_16x16x32_bf16(a[i], b[j], acc[i][j], 0, 0, 0);
        }
        __syncthreads();
    }

    // epilogue: D col = lane&15 = px, row = kg*4 + r = oc-within-frag
    #pragma unroll
    for (int i = 0; i < WM; ++i) {
        int oc = ocbase + (mw * WM + i) * 16 + kg * 4;
        #pragma unroll
        for (int j = 0; j < WN; ++j) {
            int nf = nw * WN + j;
            int gy = y0 + nf, gx = x0 + l15;
            ushort4 pk;
            pk.x = f2bf(lrelu(acc[i][j][0]));
            pk.y = f2bf(lrelu(acc[i][j][1]));
            pk.z = f2bf(lrelu(acc[i][j][2]));
            pk.w = f2bf(lrelu(acc[i][j][3]));
            *(ushort4*)&out[((size_t)(n * H + gy) * H + gx) * COUT + oc] = pk;
        }
    }
}

// ---------------------------------------------------------------------------
// Encoder conv1: 7x7 pad3, Cin=1, Cout=16, both frames in one launch (z=0..63)
// ---------------------------------------------------------------------------
__global__ __launch_bounds__(256) void conv1_tiled(
    const float* __restrict__ fA, const float* __restrict__ fB,
    const float* __restrict__ w, const float* __restrict__ bias,
    float* __restrict__ out)
{
    __shared__ float s_in[38][40];
    __shared__ float s_w[49][8];

    const int tid = threadIdx.x;
    const int tx = tid & 15, ty = tid >> 4;
    const int tile = blockIdx.x;
    const int x0 = (tile & 1) << 5;
    const int y0 = (tile >> 1) << 5;
    const int ocbase = blockIdx.y * 8;
    const int n = blockIdx.z;
    const float* in = (n < BATCH) ? (fA + (size_t)n * 4096) : (fB + (size_t)(n - BATCH) * 4096);

    for (int t = tid; t < 49 * 8; t += 256) {
        int oc = t & 7, k = t >> 3;
        s_w[k][oc] = w[(ocbase + oc) * 49 + k];
    }
    for (int t = tid; t < 38 * 38; t += 256) {
        int y = t / 38, x = t - (t / 38) * 38;
        int gy = y0 + y - 3, gx = x0 + x - 3;
        float v = 0.f;
        if ((unsigned)gy < 64u && (unsigned)gx < 64u) v = in[gy * 64 + gx];
        s_in[y][x] = v;
    }
    __syncthreads();

    float acc[8][4];
    #pragma unroll
    for (int oc = 0; oc < 8; ++oc) {
        float bv = bias[ocbase + oc];
        acc[oc][0] = bv; acc[oc][1] = bv; acc[oc][2] = bv; acc[oc][3] = bv;
    }
    #pragma unroll
    for (int kh = 0; kh < 7; ++kh) {
        #pragma unroll
        for (int kw = 0; kw < 7; ++kw) {
            float i00 = s_in[ty + kh][tx + kw];
            float i01 = s_in[ty + kh][tx + 16 + kw];
            float i10 = s_in[ty + 16 + kh][tx + kw];
            float i11 = s_in[ty + 16 + kh][tx + 16 + kw];
            #pragma unroll
            for (int oc = 0; oc < 8; ++oc) {
                float wv = s_w[kh * 7 + kw][oc];
                acc[oc][0] = fmaf(i00, wv, acc[oc][0]);
                acc[oc][1] = fmaf(i01, wv, acc[oc][1]);
                acc[oc][2] = fmaf(i10, wv, acc[oc][2]);
                acc[oc][3] = fmaf(i11, wv, acc[oc][3]);
            }
        }
    }
    #pragma unroll
    for (int oc = 0; oc < 8; ++oc)
        #pragma unroll
        for (int i = 0; i < 2; ++i)
            #pragma unroll
            for (int j = 0; j < 2; ++j) {
                int oy = y0 + ty + i * 16, ox = x0 + tx + j * 16;
                out[((size_t)n * 16 + ocbase + oc) * 4096 + oy * 64 + ox] = acc[oc][i * 2 + j];
            }
}

// ---------------------------------------------------------------------------
// Encoder conv2: 5x5 s2 pad2, 16->32, 64->32. NCHW f32.
// ---------------------------------------------------------------------------
__global__ __launch_bounds__(256) void conv2_tiled(
    const float* __restrict__ in, const float* __restrict__ w,
    const float* __restrict__ bias, float* __restrict__ out)
{
    __shared__ float s_in[2][67][68];
    __shared__ float s_w[2][25][4];

    const int tid = threadIdx.x;
    const int tx = tid & 15, ty = tid >> 4;
    const int ocbase = blockIdx.y * 4;
    const int n = blockIdx.z;

    float acc[4][4];
    #pragma unroll
    for (int oc = 0; oc < 4; ++oc) {
        float bv = bias[ocbase + oc];
        acc[oc][0] = bv; acc[oc][1] = bv; acc[oc][2] = bv; acc[oc][3] = bv;
    }

    for (int c0 = 0; c0 < 16; c0 += 2) {
        for (int t = tid; t < 2 * 25 * 4; t += 256) {
            int oc = t & 3;
            int k  = (t >> 2) % 25;
            int ic = t / 100;
            s_w[ic][k][oc] = w[((ocbase + oc) * 16 + c0 + ic) * 25 + k];
        }
        for (int t = tid; t < 2 * 67 * 67; t += 256) {
            int ic = t / 4489;
            int r  = t - ic * 4489;
            int y = r / 67, x = r - (r / 67) * 67;
            int gy = y - 2, gx = x - 2;
            float v = 0.f;
            if ((unsigned)gy < 64u && (unsigned)gx < 64u)
                v = in[((size_t)n * 16 + c0 + ic) * 4096 + gy * 64 + gx];
            s_in[ic][y][x] = v;
        }
        __syncthreads();

        #pragma unroll
        for (int ic = 0; ic < 2; ++ic)
            #pragma unroll
            for (int kh = 0; kh < 5; ++kh)
                #pragma unroll
                for (int kw = 0; kw < 5; ++kw) {
                    float i00 = s_in[ic][2 * ty + kh][2 * tx + kw];
                    float i01 = s_in[ic][2 * ty + kh][2 * tx + 32 + kw];
                    float i10 = s_in[ic][2 * ty + 32 + kh][2 * tx + kw];
                    float i11 = s_in[ic][2 * ty + 32 + kh][2 * tx + 32 + kw];
                    #pragma unroll
                    for (int oc = 0; oc < 4; ++oc) {
                        float wv = s_w[ic][kh * 5 + kw][oc];
                        acc[oc][0] = fmaf(i00, wv, acc[oc][0]);
                        acc[oc][1] = fmaf(i01, wv, acc[oc][1]);
                        acc[oc][2] = fmaf(i10, wv, acc[oc][2]);
                        acc[oc][3] = fmaf(i11, wv, acc[oc][3]);
                    }
                }
        __syncthreads();
    }

    #pragma unroll
    for (int oc = 0; oc < 4; ++oc)
        #pragma unroll
        for (int i = 0; i < 2; ++i)
            #pragma unroll
            for (int j = 0; j < 2; ++j) {
                int oy = ty + i * 16, ox = tx + j * 16;
                out[((size_t)n * 32 + ocbase + oc) * 1024 + oy * 32 + ox] = acc[oc][i * 2 + j];
            }
}

// ---------------------------------------------------------------------------
// Encoder conv3 (fp32 tiled 3x3), NCHW
// ---------------------------------------------------------------------------
template<int OCB, bool RELU>
__global__ __launch_bounds__(256) void conv3x3_tiled(
    const float* __restrict__ in, const float* __restrict__ w,
    const float* __restrict__ bias, float* __restrict__ out,
    int CIN, int H, int COUT)
{
    __shared__ float s_in[4][34][40];
    __shared__ float s_w[4][9][OCB];

    const int tid = threadIdx.x;
    const int tx = tid & 15, ty = tid >> 4;
    const int tilesx = H >> 5;
    const int tile = blockIdx.x;
    const int x0 = (tile % tilesx) << 5;
    const int y0 = (tile / tilesx) << 5;
    const int ocbase = blockIdx.y * OCB;
    const int n = blockIdx.z;

    float acc[OCB][4];
    #pragma unroll
    for (int oc = 0; oc < OCB; ++oc) {
        float bv = bias[ocbase + oc];
        acc[oc][0] = bv; acc[oc][1] = bv; acc[oc][2] = bv; acc[oc][3] = bv;
    }

    for (int c0 = 0; c0 < CIN; c0 += 4) {
        for (int t = tid; t < 4 * 9 * OCB; t += 256) {
            int oc = t % OCB;
            int k  = (t / OCB) % 9;
            int ic = t / (OCB * 9);
            s_w[ic][k][oc] = w[((size_t)(ocbase + oc) * CIN + c0 + ic) * 9 + k];
        }
        for (int t = tid; t < 4 * 34 * 34; t += 256) {
            int ic = t / 1156;
            int r  = t - ic * 1156;
            int y = r / 34, x = r - (r / 34) * 34;
            int gy = y0 + y - 1, gx = x0 + x - 1;
            float v = 0.f;
            if ((unsigned)gy < (unsigned)H && (unsigned)gx < (unsigned)H)
                v = in[((size_t)n * CIN + c0 + ic) * H * H + gy * H + gx];
            s_in[ic][y][x] = v;
        }
        __syncthreads();

        #pragma unroll
        for (int ic = 0; ic < 4; ++ic)
            #pragma unroll
            for (int kh = 0; kh < 3; ++kh)
                #pragma unroll
                for (int kw = 0; kw < 3; ++kw) {
                    float i00 = s_in[ic][ty + kh][tx + kw];
                    float i01 = s_in[ic][ty + kh][tx + 16 + kw];
                    float i10 = s_in[ic][ty + 16 + kh][tx + kw];
                    float i11 = s_in[ic][ty + 16 + kh][tx + 16 + kw];
                    #pragma unroll
                    for (int oc = 0; oc < OCB; ++oc) {
                        float wv = s_w[ic][kh * 3 + kw][oc];
                        acc[oc][0] = fmaf(i00, wv, acc[oc][0]);
                        acc[oc][1] = fmaf(i01, wv, acc[oc][1]);
                        acc[oc][2] = fmaf(i10, wv, acc[oc][2]);
                        acc[oc][3] = fmaf(i11, wv, acc[oc][3]);
                    }
                }
        __syncthreads();
    }

    #pragma unroll
    for (int oc = 0; oc < OCB; ++oc)
        #pragma unroll
        for (int i = 0; i < 2; ++i)
            #pragma unroll
            for (int j = 0; j < 2; ++j) {
                int oy = y0 + ty + i * 16, ox = x0 + tx + j * 16;
                float v = acc[oc][i * 2 + j];
                if (RELU) v = lrelu(v);
                out[((size_t)n * COUT + ocbase + oc) * H * H + oy * H + ox] = v;
            }
}

// ---------------------------------------------------------------------------
// BN stats: one block per (frame, channel). x (2,B,C,HW) NCHW f32.
// ---------------------------------------------------------------------------
__global__ void bn_stats_kernel(const float* __restrict__ x, float* __restrict__ stats,
                                int C, int HW)
{
    int c = blockIdx.x % C;
    int f = blockIdx.x / C;
    const float* base = x + (size_t)f * BATCH * C * HW + (size_t)c * HW;
    int total = BATCH * HW;
    float s = 0.f, s2 = 0.f;
    for (int i = threadIdx.x; i < total; i += blockDim.x) {
        int b = i / HW;
        int p = i - b * HW;
        float v = base[(size_t)b * C * HW + p];
        s += v; s2 += v * v;
    }
    __shared__ float sh1[256], sh2[256];
    sh1[threadIdx.x] = s; sh2[threadIdx.x] = s2;
    __syncthreads();
    for (int off = 128; off > 0; off >>= 1) {
        if (threadIdx.x < off) {
            sh1[threadIdx.x] += sh1[threadIdx.x + off];
            sh2[threadIdx.x] += sh2[threadIdx.x + off];
        }
        __syncthreads();
    }
    if (threadIdx.x == 0) {
        float inv = 1.f / (float)total;
        float m   = sh1[0] * inv;
        float var = sh2[0] * inv - m * m;
        stats[2 * blockIdx.x]     = m;
        stats[2 * blockIdx.x + 1] = rsqrtf(var + BN_EPS);
    }
}

// BN+lrelu in-place (layer 2)
__global__ void bn_apply_kernel(float* __restrict__ x, const float* __restrict__ stats,
                                const float* __restrict__ g, const float* __restrict__ be,
                                int C, int HW, int total)
{
    int idx = blockIdx.x * blockDim.x + threadIdx.x;
    if (idx >= total) return;
    int c = (idx / HW) % C;
    int f = idx / (BATCH * C * HW);
    float m = stats[2 * (f * C + c)];
    float r = stats[2 * (f * C + c) + 1];
    x[idx] = lrelu((x[idx] - m) * r * g[c] + be[c]);
}

// BN+lrelu layer 1: in-place f32 NCHW + bf16 NHWC skip copy [2*B][64][64][16]
__global__ void bn_apply1_kernel(float* __restrict__ x, const float* __restrict__ stats,
                                 const float* __restrict__ g, const float* __restrict__ be,
                                 unsigned short* __restrict__ skipN)
{
    int idx = blockIdx.x * blockDim.x + threadIdx.x;
    if (idx >= 2 * BATCH * 16 * 4096) return;
    int p  = idx & 4095;
    int c  = (idx >> 12) & 15;
    int nn = idx >> 16;           // f*B+n
    int f  = nn >> 5;
    float m = stats[2 * (f * 16 + c)];
    float r = stats[2 * (f * 16 + c) + 1];
    float v = lrelu((x[idx] - m) * r * g[c] + be[c]);
    x[idx] = v;
    skipN[((size_t)nn * 4096 + p) * 16 + c] = f2bf(v);
}

// BN3 + lrelu + channel L2-norm, NCHW f32 -> NHWC f32 [2*B][1024][32]
__global__ void bn3_l2n_kernel(const float* __restrict__ x, const float* __restrict__ stats,
                               const float* __restrict__ g, const float* __restrict__ be,
                               float* __restrict__ outN)
{
    int idx = blockIdx.x * blockDim.x + threadIdx.x;
    if (idx >= 2 * BATCH * 1024) return;
    int hw = idx & 1023;
    int nn = idx >> 10;           // f*B+n
    int f  = nn >> 5;
    float v[32];
    float ss = 0.f;
    #pragma unroll
    for (int c = 0; c < 32; ++c) {
        float m = stats[2 * (f * 32 + c)];
        float r = stats[2 * (f * 32 + c) + 1];
        float t = lrelu((x[((size_t)nn * 32 + c) * 1024 + hw] - m) * r * g[c] + be[c]);
        v[c] = t; ss += t * t;
    }
    float inv = 1.f / fmaxf(sqrtf(ss), 1e-12f);
    float* dst = outN + (size_t)idx * 32;
    #pragma unroll
    for (int c = 0; c < 32; ++c) dst[c] = v[c] * inv;
}

// ---------------------------------------------------------------------------
// Correlation: coarseN NHWC f32 [2*B][32][32][32] -> cost NHWC bf16 [B][32][32][192]
// block = 192 threads (one per displacement, incl. 23 zero-pad), grid (1024,B)
// ---------------------------------------------------------------------------
__global__ __launch_bounds__(192) void corr_nhwc(const float* __restrict__ xN,
                                                 unsigned short* __restrict__ cost)
{
    int hw = blockIdx.x, b = blockIdx.y;
    int h = hw >> 5, w_ = hw & 31;
    int d = threadIdx.x;
    int dy = d / 13 - 6, dx = d - (d / 13) * 13 - 6;
    int hb = h + dy, wb = w_ + dx;
    float s = 0.f;
    if (d < 169 && (unsigned)hb < 32u && (unsigned)wb < 32u) {
        const f32x4* A = (const f32x4*)(xN + ((size_t)b * 1024 + hw) * 32);
        const f32x4* B = (const f32x4*)(xN + ((size_t)(BATCH + b) * 1024 + hb * 32 + wb) * 32);
        #pragma unroll
        for (int q = 0; q < 8; ++q) {
            f32x4 av = A[q], bv = B[q];
            s += av.x * bv.x + av.y * bv.y + av.z * bv.z + av.w * bv.w;
        }
    }
    cost[((size_t)b * 1024 + hw) * 192 + d] = f2bf(s);
}

// ---------------------------------------------------------------------------
// Final 1x1 conv: f2o NHWC bf16 [B][4096][32] -> out NCHW f32 (B,2,64,64)
// ---------------------------------------------------------------------------
__global__ void conv_out_bf16(const unsigned short* __restrict__ x, const float* __restrict__ w,
                              const float* __restrict__ bias, float* __restrict__ out)
{
    int idx = blockIdx.x * blockDim.x + threadIdx.x;
    if (idx >= BATCH * 4096) return;
    const int4* xq = (const int4*)(x + (size_t)idx * 32);
    float s0 = bias[0], s1 = bias[1];
    #pragma unroll
    for (int q = 0; q < 4; ++q) {
        int4 vq = xq[q];
        int e[4] = {vq.x, vq.y, vq.z, vq.w};
        #pragma unroll
        for (int k = 0; k < 4; ++k) {
            int c = q * 8 + k * 2;
            float v0 = __uint_as_float(((unsigned)e[k]) << 16);
            float v1 = __uint_as_float(((unsigned)e[k]) & 0xFFFF0000u);
            s0 = fmaf(v0, w[c], s0);     s1 = fmaf(v0, w[32 + c], s1);
            s0 = fmaf(v1, w[c + 1], s0); s1 = fmaf(v1, w[32 + c + 1], s1);
        }
    }
    int n = idx >> 12, p = idx & 4095;
    out[((size_t)n * 2) * 4096 + p]     = s0;
    out[((size_t)n * 2 + 1) * 4096 + p] = s1;
}

// ---------------------------------------------------------------------------
extern "C" void kernel_launch(void* const* d_in, const int* in_sizes, int n_in,
                              void* d_out, int out_size, void* d_ws, size_t ws_size,
                              hipStream_t stream)
{
    const float* frameA = (const float*)d_in[0];
    const float* frameB = (const float*)d_in[1];
    const float* w1  = (const float*)d_in[2];
    const float* b1  = (const float*)d_in[3];
    const float* g1  = (const float*)d_in[4];
    const float* be1 = (const float*)d_in[5];
    const float* w2  = (const float*)d_in[6];
    const float* b2  = (const float*)d_in[7];
    const float* g2  = (const float*)d_in[8];
    const float* be2 = (const float*)d_in[9];
    const float* w3  = (const float*)d_in[10];
    const float* b3  = (const float*)d_in[11];
    const float* g3  = (const float*)d_in[12];
    const float* be3 = (const float*)d_in[13];
    const float* wc1 = (const float*)d_in[14];
    const float* bc1 = (const float*)d_in[15];
    const float* wc2 = (const float*)d_in[16];
    const float* bc2 = (const float*)d_in[17];
    const float* wf1 = (const float*)d_in[18];
    const float* bf1 = (const float*)d_in[19];
    const float* wf2 = (const float*)d_in[20];
    const float* bf2 = (const float*)d_in[21];
    const float* wo  = (const float*)d_in[22];
    const float* bo  = (const float*)d_in[23];

    // workspace layout
    float* ws      = (float*)d_ws;
    float* fine    = ws;                    // (2,B,16,64,64) f32   4,194,304
    float* h2      = fine + 4194304;        // (2,B,32,32,32) f32   2,097,152
    float* coarse3 = h2 + 2097152;          // (2,B,32,32,32) f32   2,097,152
    float* coarseN = coarse3 + 2097152;     // [2B][1024][32] f32   2,097,152
    float* stats   = coarseN + 2097152;     // 256
    unsigned short* fineN = (unsigned short*)(stats + 256);  // [2B][64][64][16]  4,194,304
    unsigned short* costN = fineN + 4194304;   // [B][32][32][192]  6,291,456
    unsigned short* d1    = costN + 6291456;   // [B][32][32][128]  4,194,304
    unsigned short* d2    = d1 + 4194304;      // [B][32][32][64]   2,097,152
    unsigned short* f1o   = d2 + 2097152;      // [B][64][64][64]   8,388,608
    unsigned short* f2o   = f1o + 8388608;     // [B][64][64][32]   4,194,304
    unsigned short* wT1   = f2o + 4194304;     // [9][128][192]       221,184
    unsigned short* wT2   = wT1 + 221184;      // [9][64][128]         73,728
    unsigned short* wTf1  = wT2 + 73728;       // [9][64][96]          55,296
    unsigned short* wTf2  = wTf1 + 55296;      // [9][32][64]          18,432

    const int T = 256;

    // weight prep (independent of activations)
    prep_w_kernel<<<cdiv(9 * 128 * 192, T), T, 0, stream>>>(wc1, wT1, 128, 169, 192);
    prep_w_kernel<<<cdiv(9 * 64 * 128, T), T, 0, stream>>>(wc2, wT2, 64, 128, 128);
    prep_w_kernel<<<cdiv(9 * 64 * 96, T), T, 0, stream>>>(wf1, wTf1, 64, 96, 96);
    prep_w_kernel<<<cdiv(9 * 32 * 64, T), T, 0, stream>>>(wf2, wTf2, 32, 64, 64);

    // encoder
    conv1_tiled<<<dim3(4, 2, 2 * BATCH), T, 0, stream>>>(frameA, frameB, w1, b1, fine);
    bn_stats_kernel<<<2 * 16, T, 0, stream>>>(fine, stats, 16, 4096);
    bn_apply1_kernel<<<cdiv(2 * BATCH * 16 * 4096, T), T, 0, stream>>>(fine, stats, g1, be1, fineN);

    conv2_tiled<<<dim3(1, 8, 2 * BATCH), T, 0, stream>>>(fine, w2, b2, h2);
    bn_stats_kernel<<<2 * 32, T, 0, stream>>>(h2, stats, 32, 1024);
    bn_apply_kernel<<<cdiv(2 * BATCH * 32 * 1024, T), T, 0, stream>>>(h2, stats, g2, be2, 32, 1024, 2 * BATCH * 32 * 1024);

    conv3x3_tiled<4, false><<<dim3(1, 8, 2 * BATCH), T, 0, stream>>>(h2, w3, b3, coarse3, 32, 32, 32);
    bn_stats_kernel<<<2 * 32, T, 0, stream>>>(coarse3, stats, 32, 1024);
    bn3_l2n_kernel<<<cdiv(2 * BATCH * 1024, T), T, 0, stream>>>(coarse3, stats, g3, be3, coarseN);

    // correlation -> bf16 NHWC cost (192 ch, zero-padded)
    corr_nhwc<<<dim3(1024, BATCH), 192, 0, stream>>>(coarseN, costN);

    // decoder (bf16 MFMA)
    conv3x3_mfma<192, 128, 32, 8, 0><<<dim3(8, 2, BATCH), T, 0, stream>>>(costN, nullptr, wT1, bc1, d1);
    conv3x3_mfma<128, 64, 32, 8, 0><<<dim3(8, 1, BATCH), T, 0, stream>>>(d1, nullptr, wT2, bc2, d2);
    conv3x3_mfma<96, 64, 64, 8, 1><<<dim3(32, 1, BATCH), T, 0, stream>>>(d2, fineN, wTf1, bf1, f1o);
    conv3x3_mfma<64, 32, 64, 16, 0><<<dim3(16, 1, BATCH), T, 0, stream>>>(f1o, nullptr, wTf2, bf2, f2o);

    conv_out_bf16<<<cdiv(BATCH * 4096, T), T, 0, stream>>>(f2o, wo, bo, (float*)d_out);
}

// Round 5
// 430.446 us; speedup vs baseline: 16.7104x; 1.5537x over previous
//
#include <hip/hip_runtime.h>

typedef __attribute__((ext_vector_type(4))) float f32x4;
typedef __attribute__((ext_vector_type(8))) short bf16x8;

#define BN_EPS 1e-5f
constexpr int BATCH = 32;

static inline int cdiv(int a, int b) { return (a + b - 1) / b; }

__device__ __forceinline__ float lrelu(float v) { return v > 0.f ? v : 0.1f * v; }

// f32 -> bf16 round-to-nearest-even
__device__ __forceinline__ unsigned short f2bf(float f) {
    unsigned u = __float_as_uint(f);
    u = (u + 0x7FFFu + ((u >> 16) & 1u)) >> 16;
    return (unsigned short)u;
}

// ---------------------------------------------------------------------------
// Weight prep (all 4 decoder weights in one launch):
// OIHW f32 -> [tap][COUT][CINP] bf16 with Cin zero-pad.
// ---------------------------------------------------------------------------
__global__ void prep_w_all(const float* w1, const float* w2, const float* w3, const float* w4,
                           unsigned short* d1, unsigned short* d2, unsigned short* d3, unsigned short* d4)
{
    // sizes: 9*128*192=221184, 9*64*128=73728, 9*64*96=55296, 9*32*64=18432
    int idx = blockIdx.x * blockDim.x + threadIdx.x;
    const float* src; unsigned short* dst; int COUT, CINS, CINP;
    if (idx < 221184)      { src = w1; dst = d1; COUT = 128; CINS = 169; CINP = 192; }
    else if (idx < 294912) { src = w2; dst = d2; COUT = 64;  CINS = 128; CINP = 128; idx -= 221184; }
    else if (idx < 350208) { src = w3; dst = d3; COUT = 64;  CINS = 96;  CINP = 96;  idx -= 294912; }
    else if (idx < 368640) { src = w4; dst = d4; COUT = 32;  CINS = 64;  CINP = 64;  idx -= 350208; }
    else return;
    int ic  = idx % CINP;
    int oc  = (idx / CINP) % COUT;
    int tap = idx / (CINP * COUT);
    float v = (ic < CINS) ? src[((size_t)oc * CINS + ic) * 9 + tap] : 0.f;
    dst[((size_t)tap * COUT + oc) * CINP + ic] = f2bf(v);
}

// ---------------------------------------------------------------------------
// MFMA implicit-GEMM 3x3 pad-1 conv, NHWC bf16 in/out, fp32 accum, lrelu.
// ---------------------------------------------------------------------------
template<int CIN, int COUT, int H, int TH, int MODE>
__global__ __launch_bounds__(256) void conv3x3_mfma(
    const unsigned short* __restrict__ in,
    const unsigned short* __restrict__ in2,
    const unsigned short* __restrict__ wT,   // [9][COUT][CIN] bf16
    const float* __restrict__ bias,
    unsigned short* __restrict__ out)        // NHWC bf16 [n][H][H][COUT]
{
    constexpr int MB = (COUT >= 64) ? 64 : COUT;
    constexpr int MFRAGS = MB / 16;
    constexpr int NFRAGS = TH;
    constexpr int WM = 2;
    constexpr int MW = MFRAGS / WM;
    constexpr int NW = 4 / MW;
    constexpr int WN = NFRAGS / NW;

    __shared__ unsigned short s_w[9 * MB * 32];
    __shared__ unsigned short s_in[(TH + 2) * 18 * 32];

    const int tid  = threadIdx.x;
    const int wid  = tid >> 6;
    const int lane = tid & 63;
    const int l15  = lane & 15;
    const int kg   = lane >> 4;
    constexpr int TILESX = H / 16;
    const int bx = blockIdx.x;
    const int x0 = (bx % TILESX) * 16;
    const int y0 = (bx / TILESX) * TH;
    const int ocbase = blockIdx.y * MB;
    const int n = blockIdx.z;

    const int mw = wid % MW;
    const int nw = wid / MW;

    f32x4 acc[WM][WN];
    #pragma unroll
    for (int i = 0; i < WM; ++i) {
        #pragma unroll
        for (int r = 0; r < 4; ++r) {
            float bv = bias[ocbase + (mw * WM + i) * 16 + kg * 4 + r];
            #pragma unroll
            for (int j = 0; j < WN; ++j) acc[i][j][r] = bv;
        }
    }

    for (int c0 = 0; c0 < CIN; c0 += 32) {
        for (int t = tid; t < 9 * MB * 4; t += 256) {
            int sub = t & 3;
            int row = t >> 2;
            int tap = row / MB, oc = row % MB;
            const unsigned short* src = wT + ((size_t)(tap * COUT + ocbase + oc) * CIN + c0) + sub * 8;
            *(int4*)&s_w[row * 32 + sub * 8] = *(const int4*)src;
        }
        for (int t = tid; t < (TH + 2) * 18 * 4; t += 256) {
            int sub = t & 3;
            int p = t >> 2;
            int y = p / 18, x = p - y * 18;
            int gy = y0 - 1 + y, gx = x0 - 1 + x;
            int4 v = {0, 0, 0, 0};
            if ((unsigned)gy < (unsigned)H && (unsigned)gx < (unsigned)H) {
                if (MODE == 0) {
                    v = *(const int4*)&in[((size_t)(n * H + gy) * H + gx) * CIN + c0 + sub * 8];
                } else {
                    if (c0 < 64) {
                        v = *(const int4*)&in[((size_t)(n * 32 + (gy >> 1)) * 32 + (gx >> 1)) * 64 + c0 + sub * 8];
                    } else {
                        int f  = sub >> 1;
                        int cc = (sub & 1) * 8;
                        v = *(const int4*)&in2[((size_t)((f * BATCH + n) * 64 + gy) * 64 + gx) * 16 + cc];
                    }
                }
            }
            *(int4*)&s_in[p * 32 + sub * 8] = v;
        }
        __syncthreads();

        #pragma unroll
        for (int tap = 0; tap < 9; ++tap) {
            const int kh = tap / 3, kw = tap - (tap / 3) * 3;
            bf16x8 a[WM], b[WN];
            #pragma unroll
            for (int i = 0; i < WM; ++i) {
                int mf = mw * WM + i;
                a[i] = *(const bf16x8*)&s_w[(tap * MB + mf * 16 + l15) * 32 + kg * 8];
            }
            #pragma unroll
            for (int j = 0; j < WN; ++j) {
                int nf = nw * WN + j;
                b[j] = *(const bf16x8*)&s_in[((nf + kh) * 18 + l15 + kw) * 32 + kg * 8];
            }
            #pragma unroll
            for (int i = 0; i < WM; ++i)
                #pragma unroll
                for (int j = 0; j < WN; ++j)
                    acc[i][j] = __builtin_amdgcn_mfma_f32_16x16x32_bf16(a[i], b[j], acc[i][j], 0, 0, 0);
        }
        __syncthreads();
    }

    #pragma unroll
    for (int i = 0; i < WM; ++i) {
        int oc = ocbase + (mw * WM + i) * 16 + kg * 4;
        #pragma unroll
        for (int j = 0; j < WN; ++j) {
            int nf = nw * WN + j;
            int gy = y0 + nf, gx = x0 + l15;
            ushort4 pk;
            pk.x = f2bf(lrelu(acc[i][j][0]));
            pk.y = f2bf(lrelu(acc[i][j][1]));
            pk.z = f2bf(lrelu(acc[i][j][2]));
            pk.w = f2bf(lrelu(acc[i][j][3]));
            *(ushort4*)&out[((size_t)(n * H + gy) * H + gx) * COUT + oc] = pk;
        }
    }
}

// ---------------------------------------------------------------------------
// Encoder conv1: 7x7 pad3, Cin=1, Cout=16, both frames (z=0..63)
// ---------------------------------------------------------------------------
__global__ __launch_bounds__(256) void conv1_tiled(
    const float* __restrict__ fA, const float* __restrict__ fB,
    const float* __restrict__ w, const float* __restrict__ bias,
    float* __restrict__ out)
{
    __shared__ float s_in[38][40];
    __shared__ float s_w[49][8];

    const int tid = threadIdx.x;
    const int tx = tid & 15, ty = tid >> 4;
    const int tile = blockIdx.x;
    const int x0 = (tile & 1) << 5;
    const int y0 = (tile >> 1) << 5;
    const int ocbase = blockIdx.y * 8;
    const int n = blockIdx.z;
    const float* in = (n < BATCH) ? (fA + (size_t)n * 4096) : (fB + (size_t)(n - BATCH) * 4096);

    for (int t = tid; t < 49 * 8; t += 256) {
        int oc = t & 7, k = t >> 3;
        s_w[k][oc] = w[(ocbase + oc) * 49 + k];
    }
    for (int t = tid; t < 38 * 38; t += 256) {
        int y = t / 38, x = t - (t / 38) * 38;
        int gy = y0 + y - 3, gx = x0 + x - 3;
        float v = 0.f;
        if ((unsigned)gy < 64u && (unsigned)gx < 64u) v = in[gy * 64 + gx];
        s_in[y][x] = v;
    }
    __syncthreads();

    float acc[8][4];
    #pragma unroll
    for (int oc = 0; oc < 8; ++oc) {
        float bv = bias[ocbase + oc];
        acc[oc][0] = bv; acc[oc][1] = bv; acc[oc][2] = bv; acc[oc][3] = bv;
    }
    #pragma unroll
    for (int kh = 0; kh < 7; ++kh) {
        #pragma unroll
        for (int kw = 0; kw < 7; ++kw) {
            float i00 = s_in[ty + kh][tx + kw];
            float i01 = s_in[ty + kh][tx + 16 + kw];
            float i10 = s_in[ty + 16 + kh][tx + kw];
            float i11 = s_in[ty + 16 + kh][tx + 16 + kw];
            #pragma unroll
            for (int oc = 0; oc < 8; ++oc) {
                float wv = s_w[kh * 7 + kw][oc];
                acc[oc][0] = fmaf(i00, wv, acc[oc][0]);
                acc[oc][1] = fmaf(i01, wv, acc[oc][1]);
                acc[oc][2] = fmaf(i10, wv, acc[oc][2]);
                acc[oc][3] = fmaf(i11, wv, acc[oc][3]);
            }
        }
    }
    #pragma unroll
    for (int oc = 0; oc < 8; ++oc)
        #pragma unroll
        for (int i = 0; i < 2; ++i)
            #pragma unroll
            for (int j = 0; j < 2; ++j) {
                int oy = y0 + ty + i * 16, ox = x0 + tx + j * 16;
                out[((size_t)n * 16 + ocbase + oc) * 4096 + oy * 64 + ox] = acc[oc][i * 2 + j];
            }
}

// ---------------------------------------------------------------------------
// Encoder conv2: 5x5 s2 pad2, 16->32, 64->32. NCHW f32.
// ---------------------------------------------------------------------------
__global__ __launch_bounds__(256) void conv2_tiled(
    const float* __restrict__ in, const float* __restrict__ w,
    const float* __restrict__ bias, float* __restrict__ out)
{
    __shared__ float s_in[2][67][68];
    __shared__ float s_w[2][25][4];

    const int tid = threadIdx.x;
    const int tx = tid & 15, ty = tid >> 4;
    const int ocbase = blockIdx.y * 4;
    const int n = blockIdx.z;

    float acc[4][4];
    #pragma unroll
    for (int oc = 0; oc < 4; ++oc) {
        float bv = bias[ocbase + oc];
        acc[oc][0] = bv; acc[oc][1] = bv; acc[oc][2] = bv; acc[oc][3] = bv;
    }

    for (int c0 = 0; c0 < 16; c0 += 2) {
        for (int t = tid; t < 2 * 25 * 4; t += 256) {
            int oc = t & 3;
            int k  = (t >> 2) % 25;
            int ic = t / 100;
            s_w[ic][k][oc] = w[((ocbase + oc) * 16 + c0 + ic) * 25 + k];
        }
        for (int t = tid; t < 2 * 67 * 67; t += 256) {
            int ic = t / 4489;
            int r  = t - ic * 4489;
            int y = r / 67, x = r - (r / 67) * 67;
            int gy = y - 2, gx = x - 2;
            float v = 0.f;
            if ((unsigned)gy < 64u && (unsigned)gx < 64u)
                v = in[((size_t)n * 16 + c0 + ic) * 4096 + gy * 64 + gx];
            s_in[ic][y][x] = v;
        }
        __syncthreads();

        #pragma unroll
        for (int ic = 0; ic < 2; ++ic)
            #pragma unroll
            for (int kh = 0; kh < 5; ++kh)
                #pragma unroll
                for (int kw = 0; kw < 5; ++kw) {
                    float i00 = s_in[ic][2 * ty + kh][2 * tx + kw];
                    float i01 = s_in[ic][2 * ty + kh][2 * tx + 32 + kw];
                    float i10 = s_in[ic][2 * ty + 32 + kh][2 * tx + kw];
                    float i11 = s_in[ic][2 * ty + 32 + kh][2 * tx + 32 + kw];
                    #pragma unroll
                    for (int oc = 0; oc < 4; ++oc) {
                        float wv = s_w[ic][kh * 5 + kw][oc];
                        acc[oc][0] = fmaf(i00, wv, acc[oc][0]);
                        acc[oc][1] = fmaf(i01, wv, acc[oc][1]);
                        acc[oc][2] = fmaf(i10, wv, acc[oc][2]);
                        acc[oc][3] = fmaf(i11, wv, acc[oc][3]);
                    }
                }
        __syncthreads();
    }

    #pragma unroll
    for (int oc = 0; oc < 4; ++oc)
        #pragma unroll
        for (int i = 0; i < 2; ++i)
            #pragma unroll
            for (int j = 0; j < 2; ++j) {
                int oy = ty + i * 16, ox = tx + j * 16;
                out[((size_t)n * 32 + ocbase + oc) * 1024 + oy * 32 + ox] = acc[oc][i * 2 + j];
            }
}

// ---------------------------------------------------------------------------
// Encoder conv3 (fp32 tiled 3x3), NCHW
// ---------------------------------------------------------------------------
template<int OCB, bool RELU>
__global__ __launch_bounds__(256) void conv3x3_tiled(
    const float* __restrict__ in, const float* __restrict__ w,
    const float* __restrict__ bias, float* __restrict__ out,
    int CIN, int H, int COUT)
{
    __shared__ float s_in[4][34][40];
    __shared__ float s_w[4][9][OCB];

    const int tid = threadIdx.x;
    const int tx = tid & 15, ty = tid >> 4;
    const int tilesx = H >> 5;
    const int tile = blockIdx.x;
    const int x0 = (tile % tilesx) << 5;
    const int y0 = (tile / tilesx) << 5;
    const int ocbase = blockIdx.y * OCB;
    const int n = blockIdx.z;

    float acc[OCB][4];
    #pragma unroll
    for (int oc = 0; oc < OCB; ++oc) {
        float bv = bias[ocbase + oc];
        acc[oc][0] = bv; acc[oc][1] = bv; acc[oc][2] = bv; acc[oc][3] = bv;
    }

    for (int c0 = 0; c0 < CIN; c0 += 4) {
        for (int t = tid; t < 4 * 9 * OCB; t += 256) {
            int oc = t % OCB;
            int k  = (t / OCB) % 9;
            int ic = t / (OCB * 9);
            s_w[ic][k][oc] = w[((size_t)(ocbase + oc) * CIN + c0 + ic) * 9 + k];
        }
        for (int t = tid; t < 4 * 34 * 34; t += 256) {
            int ic = t / 1156;
            int r  = t - ic * 1156;
            int y = r / 34, x = r - (r / 34) * 34;
            int gy = y0 + y - 1, gx = x0 + x - 1;
            float v = 0.f;
            if ((unsigned)gy < (unsigned)H && (unsigned)gx < (unsigned)H)
                v = in[((size_t)n * CIN + c0 + ic) * H * H + gy * H + gx];
            s_in[ic][y][x] = v;
        }
        __syncthreads();

        #pragma unroll
        for (int ic = 0; ic < 4; ++ic)
            #pragma unroll
            for (int kh = 0; kh < 3; ++kh)
                #pragma unroll
                for (int kw = 0; kw < 3; ++kw) {
                    float i00 = s_in[ic][ty + kh][tx + kw];
                    float i01 = s_in[ic][ty + kh][tx + 16 + kw];
                    float i10 = s_in[ic][ty + 16 + kh][tx + kw];
                    float i11 = s_in[ic][ty + 16 + kh][tx + 16 + kw];
                    #pragma unroll
                    for (int oc = 0; oc < OCB; ++oc) {
                        float wv = s_w[ic][kh * 3 + kw][oc];
                        acc[oc][0] = fmaf(i00, wv, acc[oc][0]);
                        acc[oc][1] = fmaf(i01, wv, acc[oc][1]);
                        acc[oc][2] = fmaf(i10, wv, acc[oc][2]);
                        acc[oc][3] = fmaf(i11, wv, acc[oc][3]);
                    }
                }
        __syncthreads();
    }

    #pragma unroll
    for (int oc = 0; oc < OCB; ++oc)
        #pragma unroll
        for (int i = 0; i < 2; ++i)
            #pragma unroll
            for (int j = 0; j < 2; ++j) {
                int oy = y0 + ty + i * 16, ox = x0 + tx + j * 16;
                float v = acc[oc][i * 2 + j];
                if (RELU) v = lrelu(v);
                out[((size_t)n * COUT + ocbase + oc) * H * H + oy * H + ox] = v;
            }
}

// ---------------------------------------------------------------------------
// Two-stage BN stats.
// Stage 1: grid (2*C, B); block 256 reduces one (f,c,b) plane of HW elems.
// Stage 2: grid (2*C); 64 threads shuffle-reduce 32 partials -> mean, rsqrt.
// ---------------------------------------------------------------------------
__global__ void bn_partial_kernel(const float* __restrict__ x, float2* __restrict__ part,
                                  int C, int HW)
{
    int fc = blockIdx.x;
    int b  = blockIdx.y;
    int c = fc % C, f = fc / C;
    const float* base = x + ((size_t)(f * BATCH + b) * C + c) * HW;
    float s = 0.f, s2 = 0.f;
    for (int i = threadIdx.x; i < HW; i += 256) {
        float v = base[i];
        s += v; s2 += v * v;
    }
    __shared__ float sh1[256], sh2[256];
    sh1[threadIdx.x] = s; sh2[threadIdx.x] = s2;
    __syncthreads();
    for (int off = 128; off > 0; off >>= 1) {
        if (threadIdx.x < off) {
            sh1[threadIdx.x] += sh1[threadIdx.x + off];
            sh2[threadIdx.x] += sh2[threadIdx.x + off];
        }
        __syncthreads();
    }
    if (threadIdx.x == 0) part[fc * BATCH + b] = make_float2(sh1[0], sh2[0]);
}

__global__ void bn_finalize_kernel(const float2* __restrict__ part, float* __restrict__ stats,
                                   int HW)
{
    int fc = blockIdx.x;
    int lane = threadIdx.x;
    float s = 0.f, s2 = 0.f;
    if (lane < BATCH) {
        float2 p = part[fc * BATCH + lane];
        s = p.x; s2 = p.y;
    }
    #pragma unroll
    for (int off = 16; off > 0; off >>= 1) {
        s  += __shfl_down(s, off);
        s2 += __shfl_down(s2, off);
    }
    if (lane == 0) {
        float inv = 1.f / (float)(BATCH * HW);
        float m   = s * inv;
        float var = s2 * inv - m * m;
        stats[2 * fc]     = m;
        stats[2 * fc + 1] = rsqrtf(var + BN_EPS);
    }
}

// BN+lrelu in-place (layer 2)
__global__ void bn_apply_kernel(float* __restrict__ x, const float* __restrict__ stats,
                                const float* __restrict__ g, const float* __restrict__ be,
                                int C, int HW, int total)
{
    int idx = blockIdx.x * blockDim.x + threadIdx.x;
    if (idx >= total) return;
    int c = (idx / HW) % C;
    int f = idx / (BATCH * C * HW);
    float m = stats[2 * (f * C + c)];
    float r = stats[2 * (f * C + c) + 1];
    x[idx] = lrelu((x[idx] - m) * r * g[c] + be[c]);
}

// BN+lrelu layer 1: in-place f32 NCHW + bf16 NHWC skip copy [2*B][64][64][16]
__global__ void bn_apply1_kernel(float* __restrict__ x, const float* __restrict__ stats,
                                 const float* __restrict__ g, const float* __restrict__ be,
                                 unsigned short* __restrict__ skipN)
{
    int idx = blockIdx.x * blockDim.x + threadIdx.x;
    if (idx >= 2 * BATCH * 16 * 4096) return;
    int p  = idx & 4095;
    int c  = (idx >> 12) & 15;
    int nn = idx >> 16;
    int f  = nn >> 5;
    float m = stats[2 * (f * 16 + c)];
    float r = stats[2 * (f * 16 + c) + 1];
    float v = lrelu((x[idx] - m) * r * g[c] + be[c]);
    x[idx] = v;
    skipN[((size_t)nn * 4096 + p) * 16 + c] = f2bf(v);
}

// BN3 + lrelu + channel L2-norm, NCHW f32 -> NHWC f32 [2*B][1024][32]
__global__ void bn3_l2n_kernel(const float* __restrict__ x, const float* __restrict__ stats,
                               const float* __restrict__ g, const float* __restrict__ be,
                               float* __restrict__ outN)
{
    int idx = blockIdx.x * blockDim.x + threadIdx.x;
    if (idx >= 2 * BATCH * 1024) return;
    int hw = idx & 1023;
    int nn = idx >> 10;
    int f  = nn >> 5;
    float v[32];
    float ss = 0.f;
    #pragma unroll
    for (int c = 0; c < 32; ++c) {
        float m = stats[2 * (f * 32 + c)];
        float r = stats[2 * (f * 32 + c) + 1];
        float t = lrelu((x[((size_t)nn * 32 + c) * 1024 + hw] - m) * r * g[c] + be[c]);
        v[c] = t; ss += t * t;
    }
    float inv = 1.f / fmaxf(sqrtf(ss), 1e-12f);
    float* dst = outN + (size_t)idx * 32;
    #pragma unroll
    for (int c = 0; c < 32; ++c) dst[c] = v[c] * inv;
}

// ---------------------------------------------------------------------------
// Correlation: coarseN NHWC f32 [2*B][32][32][32] -> cost NHWC bf16 [B][32][32][192]
// ---------------------------------------------------------------------------
__global__ __launch_bounds__(192) void corr_nhwc(const float* __restrict__ xN,
                                                 unsigned short* __restrict__ cost)
{
    int hw = blockIdx.x, b = blockIdx.y;
    int h = hw >> 5, w_ = hw & 31;
    int d = threadIdx.x;
    int dy = d / 13 - 6, dx = d - (d / 13) * 13 - 6;
    int hb = h + dy, wb = w_ + dx;
    float s = 0.f;
    if (d < 169 && (unsigned)hb < 32u && (unsigned)wb < 32u) {
        const f32x4* A = (const f32x4*)(xN + ((size_t)b * 1024 + hw) * 32);
        const f32x4* B = (const f32x4*)(xN + ((size_t)(BATCH + b) * 1024 + hb * 32 + wb) * 32);
        #pragma unroll
        for (int q = 0; q < 8; ++q) {
            f32x4 av = A[q], bv = B[q];
            s += av.x * bv.x + av.y * bv.y + av.z * bv.z + av.w * bv.w;
        }
    }
    cost[((size_t)b * 1024 + hw) * 192 + d] = f2bf(s);
}

// ---------------------------------------------------------------------------
// Final 1x1 conv: f2o NHWC bf16 [B][4096][32] -> out NCHW f32 (B,2,64,64)
// ---------------------------------------------------------------------------
__global__ void conv_out_bf16(const unsigned short* __restrict__ x, const float* __restrict__ w,
                              const float* __restrict__ bias, float* __restrict__ out)
{
    int idx = blockIdx.x * blockDim.x + threadIdx.x;
    if (idx >= BATCH * 4096) return;
    const int4* xq = (const int4*)(x + (size_t)idx * 32);
    float s0 = bias[0], s1 = bias[1];
    #pragma unroll
    for (int q = 0; q < 4; ++q) {
        int4 vq = xq[q];
        int e[4] = {vq.x, vq.y, vq.z, vq.w};
        #pragma unroll
        for (int k = 0; k < 4; ++k) {
            int c = q * 8 + k * 2;
            float v0 = __uint_as_float(((unsigned)e[k]) << 16);
            float v1 = __uint_as_float(((unsigned)e[k]) & 0xFFFF0000u);
            s0 = fmaf(v0, w[c], s0);     s1 = fmaf(v0, w[32 + c], s1);
            s0 = fmaf(v1, w[c + 1], s0); s1 = fmaf(v1, w[32 + c + 1], s1);
        }
    }
    int n = idx >> 12, p = idx & 4095;
    out[((size_t)n * 2) * 4096 + p]     = s0;
    out[((size_t)n * 2 + 1) * 4096 + p] = s1;
}

// ---------------------------------------------------------------------------
extern "C" void kernel_launch(void* const* d_in, const int* in_sizes, int n_in,
                              void* d_out, int out_size, void* d_ws, size_t ws_size,
                              hipStream_t stream)
{
    const float* frameA = (const float*)d_in[0];
    const float* frameB = (const float*)d_in[1];
    const float* w1  = (const float*)d_in[2];
    const float* b1  = (const float*)d_in[3];
    const float* g1  = (const float*)d_in[4];
    const float* be1 = (const float*)d_in[5];
    const float* w2  = (const float*)d_in[6];
    const float* b2  = (const float*)d_in[7];
    const float* g2  = (const float*)d_in[8];
    const float* be2 = (const float*)d_in[9];
    const float* w3  = (const float*)d_in[10];
    const float* b3  = (const float*)d_in[11];
    const float* g3  = (const float*)d_in[12];
    const float* be3 = (const float*)d_in[13];
    const float* wc1 = (const float*)d_in[14];
    const float* bc1 = (const float*)d_in[15];
    const float* wc2 = (const float*)d_in[16];
    const float* bc2 = (const float*)d_in[17];
    const float* wf1 = (const float*)d_in[18];
    const float* bf1 = (const float*)d_in[19];
    const float* wf2 = (const float*)d_in[20];
    const float* bf2 = (const float*)d_in[21];
    const float* wo  = (const float*)d_in[22];
    const float* bo  = (const float*)d_in[23];

    // workspace layout
    float* ws      = (float*)d_ws;
    float* fine    = ws;                    // (2,B,16,64,64) f32   4,194,304
    float* h2      = fine + 4194304;        // (2,B,32,32,32) f32   2,097,152
    float* coarse3 = h2 + 2097152;          // (2,B,32,32,32) f32   2,097,152
    float* coarseN = coarse3 + 2097152;     // [2B][1024][32] f32   2,097,152
    float* stats   = coarseN + 2097152;     // 256
    float2* part   = (float2*)(stats + 256);  // up to 64*32 float2
    unsigned short* fineN = (unsigned short*)(stats + 256 + 4096);  // [2B][64][64][16]  4,194,304
    unsigned short* costN = fineN + 4194304;   // [B][32][32][192]  6,291,456
    unsigned short* d1    = costN + 6291456;   // [B][32][32][128]  4,194,304
    unsigned short* d2    = d1 + 4194304;      // [B][32][32][64]   2,097,152
    unsigned short* f1o   = d2 + 2097152;      // [B][64][64][64]   8,388,608
    unsigned short* f2o   = f1o + 8388608;     // [B][64][64][32]   4,194,304
    unsigned short* wT1   = f2o + 4194304;     // [9][128][192]       221,184
    unsigned short* wT2   = wT1 + 221184;      // [9][64][128]         73,728
    unsigned short* wTf1  = wT2 + 73728;       // [9][64][96]          55,296
    unsigned short* wTf2  = wTf1 + 55296;      // [9][32][64]          18,432

    const int T = 256;

    // decoder weight prep (single launch)
    prep_w_all<<<cdiv(368640, T), T, 0, stream>>>(wc1, wc2, wf1, wf2, wT1, wT2, wTf1, wTf2);

    // encoder layer 1
    conv1_tiled<<<dim3(4, 2, 2 * BATCH), T, 0, stream>>>(frameA, frameB, w1, b1, fine);
    bn_partial_kernel<<<dim3(2 * 16, BATCH), T, 0, stream>>>(fine, part, 16, 4096);
    bn_finalize_kernel<<<2 * 16, 64, 0, stream>>>(part, stats, 4096);
    bn_apply1_kernel<<<cdiv(2 * BATCH * 16 * 4096, T), T, 0, stream>>>(fine, stats, g1, be1, fineN);

    // encoder layer 2
    conv2_tiled<<<dim3(1, 8, 2 * BATCH), T, 0, stream>>>(fine, w2, b2, h2);
    bn_partial_kernel<<<dim3(2 * 32, BATCH), T, 0, stream>>>(h2, part, 32, 1024);
    bn_finalize_kernel<<<2 * 32, 64, 0, stream>>>(part, stats, 1024);
    bn_apply_kernel<<<cdiv(2 * BATCH * 32 * 1024, T), T, 0, stream>>>(h2, stats, g2, be2, 32, 1024, 2 * BATCH * 32 * 1024);

    // encoder layer 3
    conv3x3_tiled<4, false><<<dim3(1, 8, 2 * BATCH), T, 0, stream>>>(h2, w3, b3, coarse3, 32, 32, 32);
    bn_partial_kernel<<<dim3(2 * 32, BATCH), T, 0, stream>>>(coarse3, part, 32, 1024);
    bn_finalize_kernel<<<2 * 32, 64, 0, stream>>>(part, stats, 1024);
    bn3_l2n_kernel<<<cdiv(2 * BATCH * 1024, T), T, 0, stream>>>(coarse3, stats, g3, be3, coarseN);

    // correlation -> bf16 NHWC cost (192 ch, zero-padded)
    corr_nhwc<<<dim3(1024, BATCH), 192, 0, stream>>>(coarseN, costN);

    // decoder (bf16 MFMA)
    conv3x3_mfma<192, 128, 32, 8, 0><<<dim3(8, 2, BATCH), T, 0, stream>>>(costN, nullptr, wT1, bc1, d1);
    conv3x3_mfma<128, 64, 32, 8, 0><<<dim3(8, 1, BATCH), T, 0, stream>>>(d1, nullptr, wT2, bc2, d2);
    conv3x3_mfma<96, 64, 64, 8, 1><<<dim3(32, 1, BATCH), T, 0, stream>>>(d2, fineN, wTf1, bf1, f1o);
    conv3x3_mfma<64, 32, 64, 16, 0><<<dim3(16, 1, BATCH), T, 0, stream>>>(f1o, nullptr, wTf2, bf2, f2o);

    conv_out_bf16<<<cdiv(BATCH * 4096, T), T, 0, stream>>>(f2o, wo, bo, (float*)d_out);
}

// Round 6
// 260.586 us; speedup vs baseline: 27.6028x; 1.6518x over previous
//
#include <hip/hip_runtime.h>

typedef __attribute__((ext_vector_type(4))) float f32x4;
typedef __attribute__((ext_vector_type(8))) short bf16x8;

#define BN_EPS 1e-5f
constexpr int BATCH = 32;

static inline int cdiv(int a, int b) { return (a + b - 1) / b; }

__device__ __forceinline__ float lrelu(float v) { return v > 0.f ? v : 0.1f * v; }

// f32 -> bf16 round-to-nearest-even
__device__ __forceinline__ unsigned short f2bf(float f) {
    unsigned u = __float_as_uint(f);
    u = (u + 0x7FFFu + ((u >> 16) & 1u)) >> 16;
    return (unsigned short)u;
}

// LDS XOR swizzle (elem units, preserves 16B granules): breaks the 64B-lane-stride
// 8-way bank conflict on ds_read_b128 fragment loads down to ~2-way (free).
#define SWZ(e) ((e) ^ ((((e) >> 6) & 3) << 3))

// ---------------------------------------------------------------------------
// Weight prep (one launch): decoder convs -> [tap][COUT][CINP] bf16 (Cin pad),
// encoder conv2 -> [13][32][32] dual-tap slots, encoder conv3 -> [9][32][32].
// ---------------------------------------------------------------------------
__global__ void prep_w_all(const float* w1, const float* w2, const float* w3, const float* w4,
                           const float* wE2s, const float* wE3s,
                           unsigned short* d1, unsigned short* d2, unsigned short* d3,
                           unsigned short* d4, unsigned short* dE2, unsigned short* dE3)
{
    int idx = blockIdx.x * blockDim.x + threadIdx.x;
    if (idx < 368640) {
        const float* src; unsigned short* dst; int COUT, CINS, CINP;
        if (idx < 221184)      { src = w1; dst = d1; COUT = 128; CINS = 169; CINP = 192; }
        else if (idx < 294912) { src = w2; dst = d2; COUT = 64;  CINS = 128; CINP = 128; idx -= 221184; }
        else if (idx < 350208) { src = w3; dst = d3; COUT = 64;  CINS = 96;  CINP = 96;  idx -= 294912; }
        else                   { src = w4; dst = d4; COUT = 32;  CINS = 64;  CINP = 64;  idx -= 350208; }
        int ic  = idx % CINP;
        int oc  = (idx / CINP) % COUT;
        int tap = idx / (CINP * COUT);
        float v = (ic < CINS) ? src[((size_t)oc * CINS + ic) * 9 + tap] : 0.f;
        dst[((size_t)tap * COUT + oc) * CINP + ic] = f2bf(v);
    } else if (idx < 381952) {               // encoder conv2: [13][32 oc][32 k]
        idx -= 368640;
        int c = idx % 32, oc = (idx / 32) % 32, s = idx / 1024;
        int tap = 2 * s + (c >= 16 ? 1 : 0);
        int ic = c & 15;
        float v = (tap < 25) ? wE2s[((size_t)oc * 16 + ic) * 25 + tap] : 0.f;
        dE2[idx] = f2bf(v);
    } else if (idx < 391168) {               // encoder conv3: [9][32][32]
        idx -= 381952;
        int ic = idx % 32, oc = (idx / 32) % 32, tap = idx / 1024;
        dE3[idx] = f2bf(wE3s[((size_t)oc * 32 + ic) * 9 + tap]);
    }
}

// ---------------------------------------------------------------------------
// MFMA implicit-GEMM 3x3 pad-1 conv, NHWC bf16 in, fp32 accum.
// OM=0: bf16 out + lrelu.  OM=1: f32 out, no activation (pre-BN).
// MODE 1 (f1): ch0-63 = upsample2x(d2), 64-95 = fineA/fineB skip.
// ---------------------------------------------------------------------------
template<int CIN, int COUT, int H, int TH, int MODE, int OM>
__global__ __launch_bounds__(256) void conv3x3_mfma(
    const unsigned short* __restrict__ in,
    const unsigned short* __restrict__ in2,
    const unsigned short* __restrict__ wT,   // [9][COUT][CIN] bf16
    const float* __restrict__ bias,
    unsigned short* __restrict__ out)
{
    constexpr int MB = (COUT >= 64) ? 64 : COUT;
    constexpr int MFRAGS = MB / 16;
    constexpr int WM = 2;
    constexpr int MW = MFRAGS / WM;
    constexpr int NW = 4 / MW;
    constexpr int WN = TH / NW;

    __shared__ unsigned short s_w[9 * MB * 32];
    __shared__ unsigned short s_in[(TH + 2) * 18 * 32];

    const int tid  = threadIdx.x;
    const int wid  = tid >> 6;
    const int lane = tid & 63;
    const int l15  = lane & 15;
    const int kg   = lane >> 4;
    constexpr int TILESX = H / 16;
    const int bx = blockIdx.x;
    const int x0 = (bx % TILESX) * 16;
    const int y0 = (bx / TILESX) * TH;
    const int ocbase = blockIdx.y * MB;
    const int n = blockIdx.z;

    const int mw = wid % MW;
    const int nw = wid / MW;

    f32x4 acc[WM][WN];
    #pragma unroll
    for (int i = 0; i < WM; ++i) {
        #pragma unroll
        for (int r = 0; r < 4; ++r) {
            float bv = bias[ocbase + (mw * WM + i) * 16 + kg * 4 + r];
            #pragma unroll
            for (int j = 0; j < WN; ++j) acc[i][j][r] = bv;
        }
    }

    for (int c0 = 0; c0 < CIN; c0 += 32) {
        for (int t = tid; t < 9 * MB * 4; t += 256) {
            int sub = t & 3;
            int row = t >> 2;
            int tap = row / MB, oc = row % MB;
            const unsigned short* src = wT + ((size_t)(tap * COUT + ocbase + oc) * CIN + c0) + sub * 8;
            *(int4*)&s_w[SWZ(row * 32 + sub * 8)] = *(const int4*)src;
        }
        for (int t = tid; t < (TH + 2) * 18 * 4; t += 256) {
            int sub = t & 3;
            int p = t >> 2;
            int y = p / 18, x = p - y * 18;
            int gy = y0 - 1 + y, gx = x0 - 1 + x;
            int4 v = {0, 0, 0, 0};
            if ((unsigned)gy < (unsigned)H && (unsigned)gx < (unsigned)H) {
                if (MODE == 0) {
                    v = *(const int4*)&in[((size_t)(n * H + gy) * H + gx) * CIN + c0 + sub * 8];
                } else {
                    if (c0 < 64) {
                        v = *(const int4*)&in[((size_t)(n * 32 + (gy >> 1)) * 32 + (gx >> 1)) * 64 + c0 + sub * 8];
                    } else {
                        int f  = sub >> 1;
                        int cc = (sub & 1) * 8;
                        v = *(const int4*)&in2[((size_t)((f * BATCH + n) * 64 + gy) * 64 + gx) * 16 + cc];
                    }
                }
            }
            *(int4*)&s_in[SWZ(p * 32 + sub * 8)] = v;
        }
        __syncthreads();

        #pragma unroll
        for (int tap = 0; tap < 9; ++tap) {
            const int kh = tap / 3, kw = tap - (tap / 3) * 3;
            bf16x8 a[WM], b[WN];
            #pragma unroll
            for (int i = 0; i < WM; ++i) {
                int mf = mw * WM + i;
                a[i] = *(const bf16x8*)&s_w[SWZ((tap * MB + mf * 16 + l15) * 32 + kg * 8)];
            }
            #pragma unroll
            for (int j = 0; j < WN; ++j) {
                int nf = nw * WN + j;
                b[j] = *(const bf16x8*)&s_in[SWZ(((nf + kh) * 18 + l15 + kw) * 32 + kg * 8)];
            }
            #pragma unroll
            for (int i = 0; i < WM; ++i)
                #pragma unroll
                for (int j = 0; j < WN; ++j)
                    acc[i][j] = __builtin_amdgcn_mfma_f32_16x16x32_bf16(a[i], b[j], acc[i][j], 0, 0, 0);
        }
        __syncthreads();
    }

    #pragma unroll
    for (int i = 0; i < WM; ++i) {
        int oc = ocbase + (mw * WM + i) * 16 + kg * 4;
        #pragma unroll
        for (int j = 0; j < WN; ++j) {
            int nf = nw * WN + j;
            int gy = y0 + nf, gx = x0 + l15;
            size_t base = ((size_t)(n * H + gy) * H + gx) * COUT + oc;
            if (OM == 0) {
                ushort4 pk;
                pk.x = f2bf(lrelu(acc[i][j][0]));
                pk.y = f2bf(lrelu(acc[i][j][1]));
                pk.z = f2bf(lrelu(acc[i][j][2]));
                pk.w = f2bf(lrelu(acc[i][j][3]));
                *(ushort4*)&out[base] = pk;
            } else {
                *(f32x4*)&((float*)out)[base] = acc[i][j];
            }
        }
    }
}

// ---------------------------------------------------------------------------
// Encoder conv2 (MFMA): 5x5 stride2 pad2, 16->32ch, 64->32. In: fineN bf16
// NHWC [64][64][64][16]. Out: f32 NHWC [64][32][32][32]. K=32 packs 2 taps.
// ---------------------------------------------------------------------------
__global__ __launch_bounds__(256) void conv2s_mfma(
    const unsigned short* __restrict__ in, const unsigned short* __restrict__ wS,
    const float* __restrict__ bias, float* __restrict__ out)
{
    __shared__ unsigned short s_w[13 * 32 * 32];     // [slot][oc32][k32]
    __shared__ unsigned short s_in[20 * 36 * 16];    // [y][x][16ch]

    const int tid = threadIdx.x;
    const int nw  = tid >> 6;                        // wave = N split (4)
    const int lane = tid & 63;
    const int l15 = lane & 15;
    const int kg  = lane >> 4;
    const int x0 = (blockIdx.x & 1) * 16;            // out col base
    const int y0 = (blockIdx.x >> 1) * 8;            // out row base
    const int n  = blockIdx.z;

    f32x4 acc[2][2];
    #pragma unroll
    for (int i = 0; i < 2; ++i) {
        #pragma unroll
        for (int r = 0; r < 4; ++r) {
            float bv = bias[i * 16 + kg * 4 + r];
            acc[i][0][r] = bv; acc[i][1][r] = bv;
        }
    }

    for (int t = tid; t < 1664; t += 256) {          // 13*32 rows * 4 subs
        int sub = t & 3, row = t >> 2;
        *(int4*)&s_w[SWZ(row * 32 + sub * 8)] = *(const int4*)&wS[row * 32 + sub * 8];
    }
    for (int t = tid; t < 1440; t += 256) {          // 20*36 px * 2 subs
        int sub = t & 1, p = t >> 1;
        int y = p / 36, x = p - y * 36;
        int gy = 2 * y0 - 2 + y, gx = 2 * x0 - 2 + x;
        int4 v = {0, 0, 0, 0};
        if ((unsigned)gy < 64u && (unsigned)gx < 64u)
            v = *(const int4*)&in[((size_t)(n * 64 + gy) * 64 + gx) * 16 + sub * 8];
        *(int4*)&s_in[SWZ((y * 36 + x) * 16 + sub * 8)] = v;
    }
    __syncthreads();

    #pragma unroll
    for (int s = 0; s < 13; ++s) {
        int tA = 2 * s, tB = 2 * s + 1;              // tB==25 -> zero weights
        int khA = tA / 5, kwA = tA % 5;
        int khB = tB / 5, kwB = tB % 5;
        int kh = (kg < 2) ? khA : khB;
        int kw = (kg < 2) ? kwA : kwB;
        int co = (kg & 1) * 8;
        bf16x8 a[2], b[2];
        a[0] = *(const bf16x8*)&s_w[SWZ((s * 32 + l15) * 32 + kg * 8)];
        a[1] = *(const bf16x8*)&s_w[SWZ((s * 32 + 16 + l15) * 32 + kg * 8)];
        #pragma unroll
        for (int j = 0; j < 2; ++j) {
            int py = nw * 2 + j;
            b[j] = *(const bf16x8*)&s_in[SWZ(((2 * py + kh) * 36 + 2 * l15 + kw) * 16 + co)];
        }
        acc[0][0] = __builtin_amdgcn_mfma_f32_16x16x32_bf16(a[0], b[0], acc[0][0], 0, 0, 0);
        acc[0][1] = __builtin_amdgcn_mfma_f32_16x16x32_bf16(a[0], b[1], acc[0][1], 0, 0, 0);
        acc[1][0] = __builtin_amdgcn_mfma_f32_16x16x32_bf16(a[1], b[0], acc[1][0], 0, 0, 0);
        acc[1][1] = __builtin_amdgcn_mfma_f32_16x16x32_bf16(a[1], b[1], acc[1][1], 0, 0, 0);
    }

    #pragma unroll
    for (int i = 0; i < 2; ++i)
        #pragma unroll
        for (int j = 0; j < 2; ++j) {
            int gy = y0 + nw * 2 + j, gx = x0 + l15;
            *(f32x4*)&out[((size_t)(n * 32 + gy) * 32 + gx) * 32 + i * 16 + kg * 4] = acc[i][j];
        }
}

// ---------------------------------------------------------------------------
// Encoder conv1: 7x7 pad3, Cin=1, Cout=16, both frames. Out NHWC f32 [64][4096][16].
// ---------------------------------------------------------------------------
__global__ __launch_bounds__(256) void conv1_tiled(
    const float* __restrict__ fA, const float* __restrict__ fB,
    const float* __restrict__ w, const float* __restrict__ bias,
    float* __restrict__ out)
{
    __shared__ float s_in[38][40];
    __shared__ float s_w[49][8];

    const int tid = threadIdx.x;
    const int tx = tid & 15, ty = tid >> 4;
    const int tile = blockIdx.x;
    const int x0 = (tile & 1) << 5;
    const int y0 = (tile >> 1) << 5;
    const int ocbase = blockIdx.y * 8;
    const int n = blockIdx.z;
    const float* in = (n < BATCH) ? (fA + (size_t)n * 4096) : (fB + (size_t)(n - BATCH) * 4096);

    for (int t = tid; t < 49 * 8; t += 256) {
        int oc = t & 7, k = t >> 3;
        s_w[k][oc] = w[(ocbase + oc) * 49 + k];
    }
    for (int t = tid; t < 38 * 38; t += 256) {
        int y = t / 38, x = t - (t / 38) * 38;
        int gy = y0 + y - 3, gx = x0 + x - 3;
        float v = 0.f;
        if ((unsigned)gy < 64u && (unsigned)gx < 64u) v = in[gy * 64 + gx];
        s_in[y][x] = v;
    }
    __syncthreads();

    float acc[8][4];
    #pragma unroll
    for (int oc = 0; oc < 8; ++oc) {
        float bv = bias[ocbase + oc];
        acc[oc][0] = bv; acc[oc][1] = bv; acc[oc][2] = bv; acc[oc][3] = bv;
    }
    #pragma unroll
    for (int kh = 0; kh < 7; ++kh) {
        #pragma unroll
        for (int kw = 0; kw < 7; ++kw) {
            float i00 = s_in[ty + kh][tx + kw];
            float i01 = s_in[ty + kh][tx + 16 + kw];
            float i10 = s_in[ty + 16 + kh][tx + kw];
            float i11 = s_in[ty + 16 + kh][tx + 16 + kw];
            #pragma unroll
            for (int oc = 0; oc < 8; ++oc) {
                float wv = s_w[kh * 7 + kw][oc];
                acc[oc][0] = fmaf(i00, wv, acc[oc][0]);
                acc[oc][1] = fmaf(i01, wv, acc[oc][1]);
                acc[oc][2] = fmaf(i10, wv, acc[oc][2]);
                acc[oc][3] = fmaf(i11, wv, acc[oc][3]);
            }
        }
    }
    #pragma unroll
    for (int i = 0; i < 2; ++i)
        #pragma unroll
        for (int j = 0; j < 2; ++j) {
            int oy = y0 + ty + i * 16, ox = x0 + tx + j * 16;
            float4 v0 = {acc[0][i * 2 + j], acc[1][i * 2 + j], acc[2][i * 2 + j], acc[3][i * 2 + j]};
            float4 v1 = {acc[4][i * 2 + j], acc[5][i * 2 + j], acc[6][i * 2 + j], acc[7][i * 2 + j]};
            float* dst = out + ((size_t)n * 4096 + oy * 64 + ox) * 16 + ocbase;
            *(float4*)dst = v0;
            *(float4*)(dst + 4) = v1;
        }
}

// ---------------------------------------------------------------------------
// BN stats on NHWC f32: stage 1 partials (coalesced), stage 2 finalize.
// x = [64][HW][C]; stats per (frame-set f, channel c).
// ---------------------------------------------------------------------------
template<int C, int NS>
__global__ void bn_part_nhwc(const float* __restrict__ x, float2* __restrict__ part, int HW)
{
    constexpr int G = 256 / C;
    int f = blockIdx.x / NS, s = blockIdx.x % NS;
    int RS = (32 * HW) / NS;
    const float* base = x + ((size_t)f * 32 * HW + (size_t)s * RS) * C;
    int c = threadIdx.x % C, rg = threadIdx.x / C;
    float s1 = 0.f, s2 = 0.f;
    for (int r = rg; r < RS; r += G) {
        float v = base[(size_t)r * C + c];
        s1 += v; s2 += v * v;
    }
    __shared__ float2 sh[256];
    sh[threadIdx.x] = make_float2(s1, s2);
    __syncthreads();
    for (int off = 128; off >= C; off >>= 1) {
        if (threadIdx.x < off) {
            float2 o = sh[threadIdx.x + off];
            sh[threadIdx.x].x += o.x; sh[threadIdx.x].y += o.y;
        }
        __syncthreads();
    }
    if (threadIdx.x < C) part[(size_t)(f * C + c) * NS + s] = sh[threadIdx.x];
}

template<int NS>
__global__ void bn_fin(const float2* __restrict__ part, float* __restrict__ stats, int HW)
{
    int fc = blockIdx.x, lane = threadIdx.x;
    float s1 = 0.f, s2 = 0.f;
    for (int k = lane; k < NS; k += 64) {
        float2 p = part[(size_t)fc * NS + k];
        s1 += p.x; s2 += p.y;
    }
    #pragma unroll
    for (int off = 32; off > 0; off >>= 1) {
        s1 += __shfl_down(s1, off);
        s2 += __shfl_down(s2, off);
    }
    if (lane == 0) {
        float inv = 1.f / (32.f * (float)HW);
        float m = s1 * inv;
        float var = s2 * inv - m * m;
        stats[2 * fc]     = m;
        stats[2 * fc + 1] = rsqrtf(var + BN_EPS);
    }
}

// BN1 apply: NHWC f32 [64][4096][16] -> NHWC bf16 (lrelu)
__global__ void bn1_apply(const float* __restrict__ xN, const float* __restrict__ stats,
                          const float* __restrict__ g, const float* __restrict__ be,
                          unsigned short* __restrict__ outN)
{
    int idx = blockIdx.x * blockDim.x + threadIdx.x;
    if (idx >= 64 * 4096) return;
    int f = idx >> 17;
    const float* src = xN + (size_t)idx * 16;
    unsigned short o[16];
    #pragma unroll
    for (int c = 0; c < 16; ++c) {
        float m = stats[2 * (f * 16 + c)], r = stats[2 * (f * 16 + c) + 1];
        o[c] = f2bf(lrelu((src[c] - m) * r * g[c] + be[c]));
    }
    int4* dst = (int4*)(outN + (size_t)idx * 16);
    dst[0] = *(int4*)&o[0];
    dst[1] = *(int4*)&o[8];
}

// BN2 apply: NHWC f32 [64][1024][32] -> NHWC bf16 (lrelu)
__global__ void bn2_apply(const float* __restrict__ xN, const float* __restrict__ stats,
                          const float* __restrict__ g, const float* __restrict__ be,
                          unsigned short* __restrict__ outN)
{
    int idx = blockIdx.x * blockDim.x + threadIdx.x;
    if (idx >= 64 * 1024) return;
    int f = idx >> 15;
    const float* src = xN + (size_t)idx * 32;
    unsigned short o[32];
    #pragma unroll
    for (int c = 0; c < 32; ++c) {
        float m = stats[2 * (f * 32 + c)], r = stats[2 * (f * 32 + c) + 1];
        o[c] = f2bf(lrelu((src[c] - m) * r * g[c] + be[c]));
    }
    int4* dst = (int4*)(outN + (size_t)idx * 32);
    #pragma unroll
    for (int q = 0; q < 4; ++q) dst[q] = *(int4*)&o[q * 8];
}

// BN3 + lrelu + channel L2 norm: NHWC f32 -> NHWC f32
__global__ void bn3_l2n_nhwc(const float* __restrict__ xN, const float* __restrict__ stats,
                             const float* __restrict__ g, const float* __restrict__ be,
                             float* __restrict__ outN)
{
    int idx = blockIdx.x * blockDim.x + threadIdx.x;
    if (idx >= 64 * 1024) return;
    int f = idx >> 15;
    const float* src = xN + (size_t)idx * 32;
    float v[32];
    float ss = 0.f;
    #pragma unroll
    for (int c = 0; c < 32; ++c) {
        float m = stats[2 * (f * 32 + c)], r = stats[2 * (f * 32 + c) + 1];
        float t = lrelu((src[c] - m) * r * g[c] + be[c]);
        v[c] = t; ss += t * t;
    }
    float inv = 1.f / fmaxf(sqrtf(ss), 1e-12f);
    float* dst = outN + (size_t)idx * 32;
    #pragma unroll
    for (int c = 0; c < 32; ++c) dst[c] = v[c] * inv;
}

// ---------------------------------------------------------------------------
// Correlation: coarseN NHWC f32 [64][1024][32] -> cost NHWC bf16 [B][1024][192]
// ---------------------------------------------------------------------------
__global__ __launch_bounds__(192) void corr_nhwc(const float* __restrict__ xN,
                                                 unsigned short* __restrict__ cost)
{
    int hw = blockIdx.x, b = blockIdx.y;
    int h = hw >> 5, w_ = hw & 31;
    int d = threadIdx.x;
    int dy = d / 13 - 6, dx = d - (d / 13) * 13 - 6;
    int hb = h + dy, wb = w_ + dx;
    float s = 0.f;
    if (d < 169 && (unsigned)hb < 32u && (unsigned)wb < 32u) {
        const f32x4* A = (const f32x4*)(xN + ((size_t)b * 1024 + hw) * 32);
        const f32x4* B = (const f32x4*)(xN + ((size_t)(BATCH + b) * 1024 + hb * 32 + wb) * 32);
        #pragma unroll
        for (int q = 0; q < 8; ++q) {
            f32x4 av = A[q], bv = B[q];
            s += av.x * bv.x + av.y * bv.y + av.z * bv.z + av.w * bv.w;
        }
    }
    cost[((size_t)b * 1024 + hw) * 192 + d] = f2bf(s);
}

// ---------------------------------------------------------------------------
// Final 1x1 conv: f2o NHWC bf16 [B][4096][32] -> out NCHW f32 (B,2,64,64)
// ---------------------------------------------------------------------------
__global__ void conv_out_bf16(const unsigned short* __restrict__ x, const float* __restrict__ w,
                              const float* __restrict__ bias, float* __restrict__ out)
{
    int idx = blockIdx.x * blockDim.x + threadIdx.x;
    if (idx >= BATCH * 4096) return;
    const int4* xq = (const int4*)(x + (size_t)idx * 32);
    float s0 = bias[0], s1 = bias[1];
    #pragma unroll
    for (int q = 0; q < 4; ++q) {
        int4 vq = xq[q];
        int e[4] = {vq.x, vq.y, vq.z, vq.w};
        #pragma unroll
        for (int k = 0; k < 4; ++k) {
            int c = q * 8 + k * 2;
            float v0 = __uint_as_float(((unsigned)e[k]) << 16);
            float v1 = __uint_as_float(((unsigned)e[k]) & 0xFFFF0000u);
            s0 = fmaf(v0, w[c], s0);     s1 = fmaf(v0, w[32 + c], s1);
            s0 = fmaf(v1, w[c + 1], s0); s1 = fmaf(v1, w[32 + c + 1], s1);
        }
    }
    int n = idx >> 12, p = idx & 4095;
    out[((size_t)n * 2) * 4096 + p]     = s0;
    out[((size_t)n * 2 + 1) * 4096 + p] = s1;
}

// ---------------------------------------------------------------------------
extern "C" void kernel_launch(void* const* d_in, const int* in_sizes, int n_in,
                              void* d_out, int out_size, void* d_ws, size_t ws_size,
                              hipStream_t stream)
{
    const float* frameA = (const float*)d_in[0];
    const float* frameB = (const float*)d_in[1];
    const float* w1  = (const float*)d_in[2];
    const float* b1  = (const float*)d_in[3];
    const float* g1  = (const float*)d_in[4];
    const float* be1 = (const float*)d_in[5];
    const float* w2  = (const float*)d_in[6];
    const float* b2  = (const float*)d_in[7];
    const float* g2  = (const float*)d_in[8];
    const float* be2 = (const float*)d_in[9];
    const float* w3  = (const float*)d_in[10];
    const float* b3  = (const float*)d_in[11];
    const float* g3  = (const float*)d_in[12];
    const float* be3 = (const float*)d_in[13];
    const float* wc1 = (const float*)d_in[14];
    const float* bc1 = (const float*)d_in[15];
    const float* wc2 = (const float*)d_in[16];
    const float* bc2 = (const float*)d_in[17];
    const float* wf1 = (const float*)d_in[18];
    const float* bf1 = (const float*)d_in[19];
    const float* wf2 = (const float*)d_in[20];
    const float* bf2 = (const float*)d_in[21];
    const float* wo  = (const float*)d_in[22];
    const float* bo  = (const float*)d_in[23];

    // workspace layout
    float* ws      = (float*)d_ws;
    float* fine1N  = ws;                    // [64][4096][16] f32   4,194,304
    float* h2N     = fine1N + 4194304;      // [64][1024][32] f32   2,097,152
    float* c3N     = h2N + 2097152;         // [64][1024][32] f32   2,097,152
    float* coarseN = c3N + 2097152;         // [64][1024][32] f32   2,097,152
    float* stats   = coarseN + 2097152;     // 256
    float2* part   = (float2*)(stats + 256);          // 16384 floats
    unsigned short* fineN = (unsigned short*)(stats + 256 + 16384);  // [64][64][64][16]
    unsigned short* h2bf  = fineN + 4194304;   // [64][32][32][32]  2,097,152
    unsigned short* costN = h2bf + 2097152;    // [B][32][32][192]  6,291,456
    unsigned short* d1    = costN + 6291456;   // [B][32][32][128]  4,194,304
    unsigned short* d2    = d1 + 4194304;      // [B][32][32][64]   2,097,152
    unsigned short* f1o   = d2 + 2097152;      // [B][64][64][64]   8,388,608
    unsigned short* f2o   = f1o + 8388608;     // [B][64][64][32]   4,194,304
    unsigned short* wT1   = f2o + 4194304;     // [9][128][192]       221,184
    unsigned short* wT2   = wT1 + 221184;      // [9][64][128]         73,728
    unsigned short* wTf1  = wT2 + 73728;       // [9][64][96]          55,296
    unsigned short* wTf2  = wTf1 + 55296;      // [9][32][64]          18,432
    unsigned short* wE2   = wTf2 + 18432;      // [13][32][32]         13,312
    unsigned short* wE3   = wE2 + 13312;       // [9][32][32]           9,216

    const int T = 256;

    // weight prep (single launch)
    prep_w_all<<<cdiv(391168, T), T, 0, stream>>>(wc1, wc2, wf1, wf2, w2, w3,
                                                  wT1, wT2, wTf1, wTf2, wE2, wE3);

    // encoder layer 1 (fp32 direct, NHWC out)
    conv1_tiled<<<dim3(4, 2, 2 * BATCH), T, 0, stream>>>(frameA, frameB, w1, b1, fine1N);
    bn_part_nhwc<16, 128><<<2 * 128, T, 0, stream>>>(fine1N, part, 4096);
    bn_fin<128><<<32, 64, 0, stream>>>(part, stats, 4096);
    bn1_apply<<<cdiv(64 * 4096, T), T, 0, stream>>>(fine1N, stats, g1, be1, fineN);

    // encoder layer 2 (MFMA, stride-2)
    conv2s_mfma<<<dim3(8, 1, 64), T, 0, stream>>>(fineN, wE2, b2, h2N);
    bn_part_nhwc<32, 128><<<2 * 128, T, 0, stream>>>(h2N, part, 1024);
    bn_fin<128><<<64, 64, 0, stream>>>(part, stats, 1024);
    bn2_apply<<<cdiv(64 * 1024, T), T, 0, stream>>>(h2N, stats, g2, be2, h2bf);

    // encoder layer 3 (MFMA)
    conv3x3_mfma<32, 32, 32, 8, 0, 1><<<dim3(8, 1, 64), T, 0, stream>>>(
        h2bf, nullptr, wE3, b3, (unsigned short*)c3N);
    bn_part_nhwc<32, 128><<<2 * 128, T, 0, stream>>>(c3N, part, 1024);
    bn_fin<128><<<64, 64, 0, stream>>>(part, stats, 1024);
    bn3_l2n_nhwc<<<cdiv(64 * 1024, T), T, 0, stream>>>(c3N, stats, g3, be3, coarseN);

    // correlation -> bf16 NHWC cost (192 ch, zero-padded)
    corr_nhwc<<<dim3(1024, BATCH), 192, 0, stream>>>(coarseN, costN);

    // decoder (bf16 MFMA)
    conv3x3_mfma<192, 128, 32, 8, 0, 0><<<dim3(8, 2, BATCH), T, 0, stream>>>(costN, nullptr, wT1, bc1, d1);
    conv3x3_mfma<128, 64, 32, 8, 0, 0><<<dim3(8, 1, BATCH), T, 0, stream>>>(d1, nullptr, wT2, bc2, d2);
    conv3x3_mfma<96, 64, 64, 8, 1, 0><<<dim3(32, 1, BATCH), T, 0, stream>>>(d2, fineN, wTf1, bf1, f1o);
    conv3x3_mfma<64, 32, 64, 16, 0, 0><<<dim3(16, 1, BATCH), T, 0, stream>>>(f1o, nullptr, wTf2, bf2, f2o);

    conv_out_bf16<<<cdiv(BATCH * 4096, T), T, 0, stream>>>(f2o, wo, bo, (float*)d_out);
}

// Round 7
// 220.595 us; speedup vs baseline: 32.6069x; 1.1813x over previous
//
#include <hip/hip_runtime.h>

typedef __attribute__((ext_vector_type(4))) float f32x4;
typedef __attribute__((ext_vector_type(8))) short bf16x8;

#define BN_EPS 1e-5f
constexpr int BATCH = 32;

static inline int cdiv(int a, int b) { return (a + b - 1) / b; }

__device__ __forceinline__ float lrelu(float v) { return v > 0.f ? v : 0.1f * v; }

// f32 -> bf16 round-to-nearest-even
__device__ __forceinline__ unsigned short f2bf(float f) {
    unsigned u = __float_as_uint(f);
    u = (u + 0x7FFFu + ((u >> 16) & 1u)) >> 16;
    return (unsigned short)u;
}

// LDS XOR swizzle (elem units, preserves 16B granules): breaks the 64B-lane-stride
// 8-way bank conflict on ds_read_b128 fragment loads down to ~2-way (free).
#define SWZ(e) ((e) ^ ((((e) >> 6) & 3) << 3))

// ---------------------------------------------------------------------------
// Weight prep (one launch): decoder convs -> [tap][COUT][CINP] bf16 (Cin pad),
// encoder conv2 -> [13][32][32] dual-tap slots, encoder conv3 -> [9][32][32].
// ---------------------------------------------------------------------------
__global__ void prep_w_all(const float* w1, const float* w2, const float* w3, const float* w4,
                           const float* wE2s, const float* wE3s,
                           unsigned short* d1, unsigned short* d2, unsigned short* d3,
                           unsigned short* d4, unsigned short* dE2, unsigned short* dE3)
{
    int idx = blockIdx.x * blockDim.x + threadIdx.x;
    if (idx < 368640) {
        const float* src; unsigned short* dst; int COUT, CINS, CINP;
        if (idx < 221184)      { src = w1; dst = d1; COUT = 128; CINS = 169; CINP = 192; }
        else if (idx < 294912) { src = w2; dst = d2; COUT = 64;  CINS = 128; CINP = 128; idx -= 221184; }
        else if (idx < 350208) { src = w3; dst = d3; COUT = 64;  CINS = 96;  CINP = 96;  idx -= 294912; }
        else                   { src = w4; dst = d4; COUT = 32;  CINS = 64;  CINP = 64;  idx -= 350208; }
        int ic  = idx % CINP;
        int oc  = (idx / CINP) % COUT;
        int tap = idx / (CINP * COUT);
        float v = (ic < CINS) ? src[((size_t)oc * CINS + ic) * 9 + tap] : 0.f;
        dst[((size_t)tap * COUT + oc) * CINP + ic] = f2bf(v);
    } else if (idx < 381952) {               // encoder conv2: [13][32 oc][32 k]
        idx -= 368640;
        int c = idx % 32, oc = (idx / 32) % 32, s = idx / 1024;
        int tap = 2 * s + (c >= 16 ? 1 : 0);
        int ic = c & 15;
        float v = (tap < 25) ? wE2s[((size_t)oc * 16 + ic) * 25 + tap] : 0.f;
        dE2[idx] = f2bf(v);
    } else if (idx < 391168) {               // encoder conv3: [9][32][32]
        idx -= 381952;
        int ic = idx % 32, oc = (idx / 32) % 32, tap = idx / 1024;
        dE3[idx] = f2bf(wE3s[((size_t)oc * 32 + ic) * 9 + tap]);
    }
}

// ---------------------------------------------------------------------------
// MFMA implicit-GEMM 3x3 pad-1 conv, NHWC bf16 in, fp32 accum.
// OM=0: bf16 out + lrelu.  OM=1: f32 out, no activation (pre-BN).
// MODE 1 (f1): ch0-63 = upsample2x(d2), 64-95 = fineA/fineB skip.
// ---------------------------------------------------------------------------
template<int CIN, int COUT, int H, int TH, int MODE, int OM>
__global__ __launch_bounds__(256) void conv3x3_mfma(
    const unsigned short* __restrict__ in,
    const unsigned short* __restrict__ in2,
    const unsigned short* __restrict__ wT,   // [9][COUT][CIN] bf16
    const float* __restrict__ bias,
    unsigned short* __restrict__ out)
{
    constexpr int MB = (COUT >= 64) ? 64 : COUT;
    constexpr int MFRAGS = MB / 16;
    constexpr int WM = 2;
    constexpr int MW = MFRAGS / WM;
    constexpr int NW = 4 / MW;
    constexpr int WN = TH / NW;

    __shared__ unsigned short s_w[9 * MB * 32];
    __shared__ unsigned short s_in[(TH + 2) * 18 * 32];

    const int tid  = threadIdx.x;
    const int wid  = tid >> 6;
    const int lane = tid & 63;
    const int l15  = lane & 15;
    const int kg   = lane >> 4;
    constexpr int TILESX = H / 16;
    const int bx = blockIdx.x;
    const int x0 = (bx % TILESX) * 16;
    const int y0 = (bx / TILESX) * TH;
    const int ocbase = blockIdx.y * MB;
    const int n = blockIdx.z;

    const int mw = wid % MW;
    const int nw = wid / MW;

    f32x4 acc[WM][WN];
    #pragma unroll
    for (int i = 0; i < WM; ++i) {
        #pragma unroll
        for (int r = 0; r < 4; ++r) {
            float bv = bias[ocbase + (mw * WM + i) * 16 + kg * 4 + r];
            #pragma unroll
            for (int j = 0; j < WN; ++j) acc[i][j][r] = bv;
        }
    }

    for (int c0 = 0; c0 < CIN; c0 += 32) {
        for (int t = tid; t < 9 * MB * 4; t += 256) {
            int sub = t & 3;
            int row = t >> 2;
            int tap = row / MB, oc = row % MB;
            const unsigned short* src = wT + ((size_t)(tap * COUT + ocbase + oc) * CIN + c0) + sub * 8;
            *(int4*)&s_w[SWZ(row * 32 + sub * 8)] = *(const int4*)src;
        }
        for (int t = tid; t < (TH + 2) * 18 * 4; t += 256) {
            int sub = t & 3;
            int p = t >> 2;
            int y = p / 18, x = p - y * 18;
            int gy = y0 - 1 + y, gx = x0 - 1 + x;
            int4 v = {0, 0, 0, 0};
            if ((unsigned)gy < (unsigned)H && (unsigned)gx < (unsigned)H) {
                if (MODE == 0) {
                    v = *(const int4*)&in[((size_t)(n * H + gy) * H + gx) * CIN + c0 + sub * 8];
                } else {
                    if (c0 < 64) {
                        v = *(const int4*)&in[((size_t)(n * 32 + (gy >> 1)) * 32 + (gx >> 1)) * 64 + c0 + sub * 8];
                    } else {
                        int f  = sub >> 1;
                        int cc = (sub & 1) * 8;
                        v = *(const int4*)&in2[((size_t)((f * BATCH + n) * 64 + gy) * 64 + gx) * 16 + cc];
                    }
                }
            }
            *(int4*)&s_in[SWZ(p * 32 + sub * 8)] = v;
        }
        __syncthreads();

        #pragma unroll
        for (int tap = 0; tap < 9; ++tap) {
            const int kh = tap / 3, kw = tap - (tap / 3) * 3;
            bf16x8 a[WM], b[WN];
            #pragma unroll
            for (int i = 0; i < WM; ++i) {
                int mf = mw * WM + i;
                a[i] = *(const bf16x8*)&s_w[SWZ((tap * MB + mf * 16 + l15) * 32 + kg * 8)];
            }
            #pragma unroll
            for (int j = 0; j < WN; ++j) {
                int nf = nw * WN + j;
                b[j] = *(const bf16x8*)&s_in[SWZ(((nf + kh) * 18 + l15 + kw) * 32 + kg * 8)];
            }
            #pragma unroll
            for (int i = 0; i < WM; ++i)
                #pragma unroll
                for (int j = 0; j < WN; ++j)
                    acc[i][j] = __builtin_amdgcn_mfma_f32_16x16x32_bf16(a[i], b[j], acc[i][j], 0, 0, 0);
        }
        __syncthreads();
    }

    #pragma unroll
    for (int i = 0; i < WM; ++i) {
        int oc = ocbase + (mw * WM + i) * 16 + kg * 4;
        #pragma unroll
        for (int j = 0; j < WN; ++j) {
            int nf = nw * WN + j;
            int gy = y0 + nf, gx = x0 + l15;
            size_t base = ((size_t)(n * H + gy) * H + gx) * COUT + oc;
            if (OM == 0) {
                ushort4 pk;
                pk.x = f2bf(lrelu(acc[i][j][0]));
                pk.y = f2bf(lrelu(acc[i][j][1]));
                pk.z = f2bf(lrelu(acc[i][j][2]));
                pk.w = f2bf(lrelu(acc[i][j][3]));
                *(ushort4*)&out[base] = pk;
            } else {
                *(f32x4*)&((float*)out)[base] = acc[i][j];
            }
        }
    }
}

// ---------------------------------------------------------------------------
// Encoder conv2 (MFMA): 5x5 stride2 pad2, 16->32ch, 64->32. In: fineN bf16
// NHWC [64][64][64][16]. Out: f32 NHWC [64][32][32][32]. K=32 packs 2 taps.
// ---------------------------------------------------------------------------
__global__ __launch_bounds__(256) void conv2s_mfma(
    const unsigned short* __restrict__ in, const unsigned short* __restrict__ wS,
    const float* __restrict__ bias, float* __restrict__ out)
{
    __shared__ unsigned short s_w[13 * 32 * 32];     // [slot][oc32][k32]
    __shared__ unsigned short s_in[20 * 36 * 16];    // [y][x][16ch]

    const int tid = threadIdx.x;
    const int nw  = tid >> 6;                        // wave = N split (4)
    const int lane = tid & 63;
    const int l15 = lane & 15;
    const int kg  = lane >> 4;
    const int x0 = (blockIdx.x & 1) * 16;            // out col base
    const int y0 = (blockIdx.x >> 1) * 8;            // out row base
    const int n  = blockIdx.z;

    f32x4 acc[2][2];
    #pragma unroll
    for (int i = 0; i < 2; ++i) {
        #pragma unroll
        for (int r = 0; r < 4; ++r) {
            float bv = bias[i * 16 + kg * 4 + r];
            acc[i][0][r] = bv; acc[i][1][r] = bv;
        }
    }

    for (int t = tid; t < 1664; t += 256) {          // 13*32 rows * 4 subs
        int sub = t & 3, row = t >> 2;
        *(int4*)&s_w[SWZ(row * 32 + sub * 8)] = *(const int4*)&wS[row * 32 + sub * 8];
    }
    for (int t = tid; t < 1440; t += 256) {          // 20*36 px * 2 subs
        int sub = t & 1, p = t >> 1;
        int y = p / 36, x = p - y * 36;
        int gy = 2 * y0 - 2 + y, gx = 2 * x0 - 2 + x;
        int4 v = {0, 0, 0, 0};
        if ((unsigned)gy < 64u && (unsigned)gx < 64u)
            v = *(const int4*)&in[((size_t)(n * 64 + gy) * 64 + gx) * 16 + sub * 8];
        *(int4*)&s_in[SWZ((y * 36 + x) * 16 + sub * 8)] = v;
    }
    __syncthreads();

    #pragma unroll
    for (int s = 0; s < 13; ++s) {
        int tA = 2 * s, tB = 2 * s + 1;              // tB==25 -> zero weights
        int khA = tA / 5, kwA = tA % 5;
        int khB = tB / 5, kwB = tB % 5;
        int kh = (kg < 2) ? khA : khB;
        int kw = (kg < 2) ? kwA : kwB;
        int co = (kg & 1) * 8;
        bf16x8 a[2], b[2];
        a[0] = *(const bf16x8*)&s_w[SWZ((s * 32 + l15) * 32 + kg * 8)];
        a[1] = *(const bf16x8*)&s_w[SWZ((s * 32 + 16 + l15) * 32 + kg * 8)];
        #pragma unroll
        for (int j = 0; j < 2; ++j) {
            int py = nw * 2 + j;
            b[j] = *(const bf16x8*)&s_in[SWZ(((2 * py + kh) * 36 + 2 * l15 + kw) * 16 + co)];
        }
        acc[0][0] = __builtin_amdgcn_mfma_f32_16x16x32_bf16(a[0], b[0], acc[0][0], 0, 0, 0);
        acc[0][1] = __builtin_amdgcn_mfma_f32_16x16x32_bf16(a[0], b[1], acc[0][1], 0, 0, 0);
        acc[1][0] = __builtin_amdgcn_mfma_f32_16x16x32_bf16(a[1], b[0], acc[1][0], 0, 0, 0);
        acc[1][1] = __builtin_amdgcn_mfma_f32_16x16x32_bf16(a[1], b[1], acc[1][1], 0, 0, 0);
    }

    #pragma unroll
    for (int i = 0; i < 2; ++i)
        #pragma unroll
        for (int j = 0; j < 2; ++j) {
            int gy = y0 + nw * 2 + j, gx = x0 + l15;
            *(f32x4*)&out[((size_t)(n * 32 + gy) * 32 + gx) * 32 + i * 16 + kg * 4] = acc[i][j];
        }
}

// ---------------------------------------------------------------------------
// Encoder conv1: 7x7 pad3, Cin=1, Cout=16, both frames. Out NHWC f32 [64][4096][16].
// ---------------------------------------------------------------------------
__global__ __launch_bounds__(256) void conv1_tiled(
    const float* __restrict__ fA, const float* __restrict__ fB,
    const float* __restrict__ w, const float* __restrict__ bias,
    float* __restrict__ out)
{
    __shared__ float s_in[38][40];
    __shared__ float s_w[49][8];

    const int tid = threadIdx.x;
    const int tx = tid & 15, ty = tid >> 4;
    const int tile = blockIdx.x;
    const int x0 = (tile & 1) << 5;
    const int y0 = (tile >> 1) << 5;
    const int ocbase = blockIdx.y * 8;
    const int n = blockIdx.z;
    const float* in = (n < BATCH) ? (fA + (size_t)n * 4096) : (fB + (size_t)(n - BATCH) * 4096);

    for (int t = tid; t < 49 * 8; t += 256) {
        int oc = t & 7, k = t >> 3;
        s_w[k][oc] = w[(ocbase + oc) * 49 + k];
    }
    for (int t = tid; t < 38 * 38; t += 256) {
        int y = t / 38, x = t - (t / 38) * 38;
        int gy = y0 + y - 3, gx = x0 + x - 3;
        float v = 0.f;
        if ((unsigned)gy < 64u && (unsigned)gx < 64u) v = in[gy * 64 + gx];
        s_in[y][x] = v;
    }
    __syncthreads();

    float acc[8][4];
    #pragma unroll
    for (int oc = 0; oc < 8; ++oc) {
        float bv = bias[ocbase + oc];
        acc[oc][0] = bv; acc[oc][1] = bv; acc[oc][2] = bv; acc[oc][3] = bv;
    }
    #pragma unroll
    for (int kh = 0; kh < 7; ++kh) {
        #pragma unroll
        for (int kw = 0; kw < 7; ++kw) {
            float i00 = s_in[ty + kh][tx + kw];
            float i01 = s_in[ty + kh][tx + 16 + kw];
            float i10 = s_in[ty + 16 + kh][tx + kw];
            float i11 = s_in[ty + 16 + kh][tx + 16 + kw];
            #pragma unroll
            for (int oc = 0; oc < 8; ++oc) {
                float wv = s_w[kh * 7 + kw][oc];
                acc[oc][0] = fmaf(i00, wv, acc[oc][0]);
                acc[oc][1] = fmaf(i01, wv, acc[oc][1]);
                acc[oc][2] = fmaf(i10, wv, acc[oc][2]);
                acc[oc][3] = fmaf(i11, wv, acc[oc][3]);
            }
        }
    }
    #pragma unroll
    for (int i = 0; i < 2; ++i)
        #pragma unroll
        for (int j = 0; j < 2; ++j) {
            int oy = y0 + ty + i * 16, ox = x0 + tx + j * 16;
            float4 v0 = {acc[0][i * 2 + j], acc[1][i * 2 + j], acc[2][i * 2 + j], acc[3][i * 2 + j]};
            float4 v1 = {acc[4][i * 2 + j], acc[5][i * 2 + j], acc[6][i * 2 + j], acc[7][i * 2 + j]};
            float* dst = out + ((size_t)n * 4096 + oy * 64 + ox) * 16 + ocbase;
            *(float4*)dst = v0;
            *(float4*)(dst + 4) = v1;
        }
}

// ---------------------------------------------------------------------------
// BN stats on NHWC f32: stage 1 partials (coalesced), stage 2 finalize.
// ---------------------------------------------------------------------------
template<int C, int NS>
__global__ void bn_part_nhwc(const float* __restrict__ x, float2* __restrict__ part, int HW)
{
    constexpr int G = 256 / C;
    int f = blockIdx.x / NS, s = blockIdx.x % NS;
    int RS = (32 * HW) / NS;
    const float* base = x + ((size_t)f * 32 * HW + (size_t)s * RS) * C;
    int c = threadIdx.x % C, rg = threadIdx.x / C;
    float s1 = 0.f, s2 = 0.f;
    for (int r = rg; r < RS; r += G) {
        float v = base[(size_t)r * C + c];
        s1 += v; s2 += v * v;
    }
    __shared__ float2 sh[256];
    sh[threadIdx.x] = make_float2(s1, s2);
    __syncthreads();
    for (int off = 128; off >= C; off >>= 1) {
        if (threadIdx.x < off) {
            float2 o = sh[threadIdx.x + off];
            sh[threadIdx.x].x += o.x; sh[threadIdx.x].y += o.y;
        }
        __syncthreads();
    }
    if (threadIdx.x < C) part[(size_t)(f * C + c) * NS + s] = sh[threadIdx.x];
}

template<int NS>
__global__ void bn_fin(const float2* __restrict__ part, float* __restrict__ stats, int HW)
{
    int fc = blockIdx.x, lane = threadIdx.x;
    float s1 = 0.f, s2 = 0.f;
    for (int k = lane; k < NS; k += 64) {
        float2 p = part[(size_t)fc * NS + k];
        s1 += p.x; s2 += p.y;
    }
    #pragma unroll
    for (int off = 32; off > 0; off >>= 1) {
        s1 += __shfl_down(s1, off);
        s2 += __shfl_down(s2, off);
    }
    if (lane == 0) {
        float inv = 1.f / (32.f * (float)HW);
        float m = s1 * inv;
        float var = s2 * inv - m * m;
        stats[2 * fc]     = m;
        stats[2 * fc + 1] = rsqrtf(var + BN_EPS);
    }
}

// BN1 apply: NHWC f32 [64][4096][16] -> NHWC bf16 (lrelu)
__global__ void bn1_apply(const float* __restrict__ xN, const float* __restrict__ stats,
                          const float* __restrict__ g, const float* __restrict__ be,
                          unsigned short* __restrict__ outN)
{
    int idx = blockIdx.x * blockDim.x + threadIdx.x;
    if (idx >= 64 * 4096) return;
    int f = idx >> 17;
    const float* src = xN + (size_t)idx * 16;
    unsigned short o[16];
    #pragma unroll
    for (int c = 0; c < 16; ++c) {
        float m = stats[2 * (f * 16 + c)], r = stats[2 * (f * 16 + c) + 1];
        o[c] = f2bf(lrelu((src[c] - m) * r * g[c] + be[c]));
    }
    int4* dst = (int4*)(outN + (size_t)idx * 16);
    dst[0] = *(int4*)&o[0];
    dst[1] = *(int4*)&o[8];
}

// BN2 apply: NHWC f32 [64][1024][32] -> NHWC bf16 (lrelu)
__global__ void bn2_apply(const float* __restrict__ xN, const float* __restrict__ stats,
                          const float* __restrict__ g, const float* __restrict__ be,
                          unsigned short* __restrict__ outN)
{
    int idx = blockIdx.x * blockDim.x + threadIdx.x;
    if (idx >= 64 * 1024) return;
    int f = idx >> 15;
    const float* src = xN + (size_t)idx * 32;
    unsigned short o[32];
    #pragma unroll
    for (int c = 0; c < 32; ++c) {
        float m = stats[2 * (f * 32 + c)], r = stats[2 * (f * 32 + c) + 1];
        o[c] = f2bf(lrelu((src[c] - m) * r * g[c] + be[c]));
    }
    int4* dst = (int4*)(outN + (size_t)idx * 32);
    #pragma unroll
    for (int q = 0; q < 4; ++q) dst[q] = *(int4*)&o[q * 8];
}

// BN3 + lrelu + channel L2 norm: NHWC f32 -> NHWC f32
__global__ void bn3_l2n_nhwc(const float* __restrict__ xN, const float* __restrict__ stats,
                             const float* __restrict__ g, const float* __restrict__ be,
                             float* __restrict__ outN)
{
    int idx = blockIdx.x * blockDim.x + threadIdx.x;
    if (idx >= 64 * 1024) return;
    int f = idx >> 15;
    const float* src = xN + (size_t)idx * 32;
    float v[32];
    float ss = 0.f;
    #pragma unroll
    for (int c = 0; c < 32; ++c) {
        float m = stats[2 * (f * 32 + c)], r = stats[2 * (f * 32 + c) + 1];
        float t = lrelu((src[c] - m) * r * g[c] + be[c]);
        v[c] = t; ss += t * t;
    }
    float inv = 1.f / fmaxf(sqrtf(ss), 1e-12f);
    float* dst = outN + (size_t)idx * 32;
    #pragma unroll
    for (int c = 0; c < 32; ++c) dst[c] = v[c] * inv;
}

// ---------------------------------------------------------------------------
// Correlation (LDS-tiled): coarseN NHWC f32 [64][1024][32] -> cost bf16
// [B][1024][192] (channels 169..191 untouched: decoder weights there are 0).
// Block = (h, b). Stage A row + 13 B rows in LDS with granule-XOR swizzle.
// ---------------------------------------------------------------------------
#define CSWZ(c, w) ((c) ^ (((w) & 7) << 2))

__global__ __launch_bounds__(256) void corr_tile(const float* __restrict__ xN,
                                                 unsigned short* __restrict__ cost)
{
    __shared__ float sA[32 * 32];
    __shared__ float sB[13][32 * 32];
    __shared__ unsigned short sC[32][176];

    const int h = blockIdx.x, b = blockIdx.y;
    const float* Ab = xN + ((size_t)b * 1024 + h * 32) * 32;
    const float* Bb = xN + ((size_t)(BATCH + b) * 1024) * 32;

    {   // stage A: 32 pos x 8 granules
        int t = threadIdx.x;
        int w = t >> 3, gr = t & 7;
        f32x4 v = *(const f32x4*)&Ab[w * 32 + gr * 4];
        *(f32x4*)&sA[w * 32 + CSWZ(gr * 4, w)] = v;
    }
    for (int t = threadIdx.x; t < 13 * 256; t += 256) {  // stage B rows h-6..h+6
        int row = t >> 8, q = t & 255;
        int w = q >> 3, gr = q & 7;
        int gh = h + row - 6;
        f32x4 v = {0.f, 0.f, 0.f, 0.f};
        if ((unsigned)gh < 32u) v = *(const f32x4*)&Bb[((size_t)gh * 32 + w) * 32 + gr * 4];
        *(f32x4*)&sB[row][w * 32 + CSWZ(gr * 4, w)] = v;
    }
    __syncthreads();

    const int w = threadIdx.x & 31;
    const int g = threadIdx.x >> 5;     // 0..7
    f32x4 a[8];
    #pragma unroll
    for (int gr = 0; gr < 8; ++gr) a[gr] = *(const f32x4*)&sA[w * 32 + CSWZ(gr * 4, w)];

    for (int dy = g; dy < 13; dy += 8) {
        #pragma unroll
        for (int dx = 0; dx < 13; ++dx) {
            int wb = w + dx - 6;
            float s = 0.f;
            if ((unsigned)wb < 32u) {
                #pragma unroll
                for (int gr = 0; gr < 8; ++gr) {
                    f32x4 bv = *(const f32x4*)&sB[dy][wb * 32 + CSWZ(gr * 4, wb)];
                    s += a[gr].x * bv.x + a[gr].y * bv.y + a[gr].z * bv.z + a[gr].w * bv.w;
                }
            }
            sC[w][dy * 13 + dx] = f2bf(s);
        }
    }
    __syncthreads();

    // coalesced copy-out: 32 pos x 169 d
    for (int t = threadIdx.x; t < 32 * 169; t += 256) {
        int ww = t / 169;
        int d  = t - ww * 169;
        cost[((size_t)(b * 1024) + h * 32 + ww) * 192 + d] = sC[ww][d];
    }
}

// ---------------------------------------------------------------------------
// Final 1x1 conv: f2o NHWC bf16 [B][4096][32] -> out NCHW f32 (B,2,64,64)
// ---------------------------------------------------------------------------
__global__ void conv_out_bf16(const unsigned short* __restrict__ x, const float* __restrict__ w,
                              const float* __restrict__ bias, float* __restrict__ out)
{
    int idx = blockIdx.x * blockDim.x + threadIdx.x;
    if (idx >= BATCH * 4096) return;
    const int4* xq = (const int4*)(x + (size_t)idx * 32);
    float s0 = bias[0], s1 = bias[1];
    #pragma unroll
    for (int q = 0; q < 4; ++q) {
        int4 vq = xq[q];
        int e[4] = {vq.x, vq.y, vq.z, vq.w};
        #pragma unroll
        for (int k = 0; k < 4; ++k) {
            int c = q * 8 + k * 2;
            float v0 = __uint_as_float(((unsigned)e[k]) << 16);
            float v1 = __uint_as_float(((unsigned)e[k]) & 0xFFFF0000u);
            s0 = fmaf(v0, w[c], s0);     s1 = fmaf(v0, w[32 + c], s1);
            s0 = fmaf(v1, w[c + 1], s0); s1 = fmaf(v1, w[32 + c + 1], s1);
        }
    }
    int n = idx >> 12, p = idx & 4095;
    out[((size_t)n * 2) * 4096 + p]     = s0;
    out[((size_t)n * 2 + 1) * 4096 + p] = s1;
}

// ---------------------------------------------------------------------------
extern "C" void kernel_launch(void* const* d_in, const int* in_sizes, int n_in,
                              void* d_out, int out_size, void* d_ws, size_t ws_size,
                              hipStream_t stream)
{
    const float* frameA = (const float*)d_in[0];
    const float* frameB = (const float*)d_in[1];
    const float* w1  = (const float*)d_in[2];
    const float* b1  = (const float*)d_in[3];
    const float* g1  = (const float*)d_in[4];
    const float* be1 = (const float*)d_in[5];
    const float* w2  = (const float*)d_in[6];
    const float* b2  = (const float*)d_in[7];
    const float* g2  = (const float*)d_in[8];
    const float* be2 = (const float*)d_in[9];
    const float* w3  = (const float*)d_in[10];
    const float* b3  = (const float*)d_in[11];
    const float* g3  = (const float*)d_in[12];
    const float* be3 = (const float*)d_in[13];
    const float* wc1 = (const float*)d_in[14];
    const float* bc1 = (const float*)d_in[15];
    const float* wc2 = (const float*)d_in[16];
    const float* bc2 = (const float*)d_in[17];
    const float* wf1 = (const float*)d_in[18];
    const float* bf1 = (const float*)d_in[19];
    const float* wf2 = (const float*)d_in[20];
    const float* bf2 = (const float*)d_in[21];
    const float* wo  = (const float*)d_in[22];
    const float* bo  = (const float*)d_in[23];

    // workspace layout
    float* ws      = (float*)d_ws;
    float* fine1N  = ws;                    // [64][4096][16] f32   4,194,304
    float* h2N     = fine1N + 4194304;      // [64][1024][32] f32   2,097,152
    float* c3N     = h2N + 2097152;         // [64][1024][32] f32   2,097,152
    float* coarseN = c3N + 2097152;         // [64][1024][32] f32   2,097,152
    float* stats   = coarseN + 2097152;     // 256
    float2* part   = (float2*)(stats + 256);          // 16384 floats
    unsigned short* fineN = (unsigned short*)(stats + 256 + 16384);  // [64][64][64][16]
    unsigned short* h2bf  = fineN + 4194304;   // [64][32][32][32]  2,097,152
    unsigned short* costN = h2bf + 2097152;    // [B][32][32][192]  6,291,456
    unsigned short* d1    = costN + 6291456;   // [B][32][32][128]  4,194,304
    unsigned short* d2    = d1 + 4194304;      // [B][32][32][64]   2,097,152
    unsigned short* f1o   = d2 + 2097152;      // [B][64][64][64]   8,388,608
    unsigned short* f2o   = f1o + 8388608;     // [B][64][64][32]   4,194,304
    unsigned short* wT1   = f2o + 4194304;     // [9][128][192]       221,184
    unsigned short* wT2   = wT1 + 221184;      // [9][64][128]         73,728
    unsigned short* wTf1  = wT2 + 73728;       // [9][64][96]          55,296
    unsigned short* wTf2  = wTf1 + 55296;      // [9][32][64]          18,432
    unsigned short* wE2   = wTf2 + 18432;      // [13][32][32]         13,312
    unsigned short* wE3   = wE2 + 13312;       // [9][32][32]           9,216

    const int T = 256;

    // weight prep (single launch)
    prep_w_all<<<cdiv(391168, T), T, 0, stream>>>(wc1, wc2, wf1, wf2, w2, w3,
                                                  wT1, wT2, wTf1, wTf2, wE2, wE3);

    // encoder layer 1 (fp32 direct, NHWC out)
    conv1_tiled<<<dim3(4, 2, 2 * BATCH), T, 0, stream>>>(frameA, frameB, w1, b1, fine1N);
    bn_part_nhwc<16, 128><<<2 * 128, T, 0, stream>>>(fine1N, part, 4096);
    bn_fin<128><<<32, 64, 0, stream>>>(part, stats, 4096);
    bn1_apply<<<cdiv(64 * 4096, T), T, 0, stream>>>(fine1N, stats, g1, be1, fineN);

    // encoder layer 2 (MFMA, stride-2)
    conv2s_mfma<<<dim3(8, 1, 64), T, 0, stream>>>(fineN, wE2, b2, h2N);
    bn_part_nhwc<32, 128><<<2 * 128, T, 0, stream>>>(h2N, part, 1024);
    bn_fin<128><<<64, 64, 0, stream>>>(part, stats, 1024);
    bn2_apply<<<cdiv(64 * 1024, T), T, 0, stream>>>(h2N, stats, g2, be2, h2bf);

    // encoder layer 3 (MFMA)
    conv3x3_mfma<32, 32, 32, 8, 0, 1><<<dim3(8, 1, 64), T, 0, stream>>>(
        h2bf, nullptr, wE3, b3, (unsigned short*)c3N);
    bn_part_nhwc<32, 128><<<2 * 128, T, 0, stream>>>(c3N, part, 1024);
    bn_fin<128><<<64, 64, 0, stream>>>(part, stats, 1024);
    bn3_l2n_nhwc<<<cdiv(64 * 1024, T), T, 0, stream>>>(c3N, stats, g3, be3, coarseN);

    // correlation (LDS-tiled) -> bf16 NHWC cost
    corr_tile<<<dim3(32, BATCH), T, 0, stream>>>(coarseN, costN);

    // decoder (bf16 MFMA)
    conv3x3_mfma<192, 128, 32, 8, 0, 0><<<dim3(8, 2, BATCH), T, 0, stream>>>(costN, nullptr, wT1, bc1, d1);
    conv3x3_mfma<128, 64, 32, 8, 0, 0><<<dim3(8, 1, BATCH), T, 0, stream>>>(d1, nullptr, wT2, bc2, d2);
    conv3x3_mfma<96, 64, 64, 8, 1, 0><<<dim3(32, 1, BATCH), T, 0, stream>>>(d2, fineN, wTf1, bf1, f1o);
    conv3x3_mfma<64, 32, 64, 16, 0, 0><<<dim3(16, 1, BATCH), T, 0, stream>>>(f1o, nullptr, wTf2, bf2, f2o);

    conv_out_bf16<<<cdiv(BATCH * 4096, T), T, 0, stream>>>(f2o, wo, bo, (float*)d_out);
}